// Round 1
// baseline (2358.615 us; speedup 1.0000x reference)
//
#include <hip/hip_runtime.h>
#include <stdint.h>

#define NBATCH 16
#define NANCH  9
#define NHGT   128
#define NWID   256
#define NHW    (NHGT * NWID)       // 32768
#define NTOT   (NHW * NANCH)       // 294912
#define PRE    6000
#define POST   300
#define CAPN   8192
#define BINS   8192
#define BIN_SHIFT 19
#define NWORDS 94                  // ceil(6000/64)

__device__ __constant__ float c_AW[NANCH] = {184.f,368.f,736.f,128.f,256.f,512.f,88.f,176.f,352.f};
__device__ __constant__ float c_AH[NANCH] = {96.f,192.f,384.f,128.f,256.f,512.f,176.f,352.f,704.f};

__device__ __forceinline__ uint32_t f2key(float f) {
    uint32_t u = __float_as_uint(f);
    return (u & 0x80000000u) ? ~u : (u | 0x80000000u);
}

// decode + clip, mirroring the reference op order; _rn intrinsics forbid fma contraction
__device__ __forceinline__ bool decode_clip(float dx, float dy, float dw, float dh,
                                            float aw, float ah, float acx, float acy,
                                            float& x1, float& y1, float& x2, float& y2) {
    float pcx = __fadd_rn(__fmul_rn(dx, aw), acx);
    float pcy = __fadd_rn(__fmul_rn(dy, ah), acy);
    float pw  = __fmul_rn(expf(dw), aw);
    float ph  = __fmul_rn(expf(dh), ah);
    float hx  = __fmul_rn(0.5f, pw);
    float hy  = __fmul_rn(0.5f, ph);
    x1 = __fsub_rn(pcx, hx);
    y1 = __fsub_rn(pcy, hy);
    x2 = __fadd_rn(pcx, hx);
    y2 = __fadd_rn(pcy, hy);
    x1 = fminf(fmaxf(x1, 0.f), 4095.f);
    x2 = fminf(fmaxf(x2, 0.f), 4095.f);
    y1 = fminf(fmaxf(y1, 0.f), 2047.f);
    y2 = fminf(fmaxf(y2, 0.f), 2047.f);
    float wpl = __fadd_rn(__fsub_rn(x2, x1), 1.f);
    float hpl = __fadd_rn(__fsub_rn(y2, y1), 1.f);
    return (wpl >= 16.f) && (hpl >= 16.f);
}

// ---------------- K1: per-batch histogram of masked-score keys ----------------
__global__ __launch_bounds__(256) void k_hist(const float* __restrict__ lab,
                                              const float* __restrict__ reg,
                                              uint32_t* __restrict__ ghist) {
    __shared__ uint32_t hist[BINS];
    for (int i = threadIdx.x; i < BINS; i += 256) hist[i] = 0;
    __syncthreads();
    int bid = blockIdx.x;
    int b = bid >> 7;                       // 128 blocks per batch
    int hw = ((bid & 127) << 8) | threadIdx.x;
    int h = hw >> 8, w = hw & 255;
    const float* lb = lab + (size_t)b * 18 * NHW + hw;
    const float* rb = reg + (size_t)b * 36 * NHW + hw;
    float acx = (float)(w * 16) + 7.5f;     // exact in fp32
    float acy = (float)(h * 16) + 7.5f;
#pragma unroll
    for (int a = 0; a < NANCH; ++a) {
        float s  = lb[(2 * a + 1) * NHW];
        float dx = rb[(4 * a + 0) * NHW];
        float dy = rb[(4 * a + 1) * NHW];
        float dwv = rb[(4 * a + 2) * NHW];
        float dhv = rb[(4 * a + 3) * NHW];
        float x1, y1, x2, y2;
        bool keep = decode_clip(dx, dy, dwv, dhv, c_AW[a], c_AH[a], acx, acy, x1, y1, x2, y2);
        float ms = keep ? s : -1e30f;
        atomicAdd(&hist[f2key(ms) >> BIN_SHIFT], 1u);
    }
    __syncthreads();
    uint32_t* gh = ghist + b * BINS;
    for (int i = threadIdx.x; i < BINS; i += 256) {
        uint32_t c = hist[i];
        if (c) atomicAdd(&gh[i], c);
    }
}

// ---------------- K2: find threshold bin (cumulative from top >= PRE) ----------------
__global__ __launch_bounds__(256) void k_thresh(const uint32_t* __restrict__ ghist,
                                                uint32_t* __restrict__ thresh) {
    __shared__ uint32_t part[256];
    int b = blockIdx.x;
    const uint32_t* gh = ghist + b * BINS;
    uint32_t s = 0;
    int base = threadIdx.x * 32;
    for (int k = 0; k < 32; ++k) s += gh[base + k];
    part[threadIdx.x] = s;
    __syncthreads();
    if (threadIdx.x == 0) {
        uint32_t cum = 0;
        int tb = 0;
        for (int c = 255; c >= 0; --c) {
            if (cum + part[c] >= (uint32_t)PRE) {
                for (int i = 31; i >= 0; --i) {
                    cum += gh[c * 32 + i];
                    if (cum >= (uint32_t)PRE) { tb = c * 32 + i; break; }
                }
                break;
            }
            cum += part[c];
        }
        thresh[b] = (uint32_t)tb << BIN_SHIFT;
    }
}

// ---------------- K3: recompute keys, compact candidates >= threshold ----------------
__global__ __launch_bounds__(256) void k_compact(const float* __restrict__ lab,
                                                 const float* __restrict__ reg,
                                                 const uint32_t* __restrict__ thresh,
                                                 uint32_t* __restrict__ cnt,
                                                 uint64_t* __restrict__ cand) {
    int bid = blockIdx.x;
    int b = bid >> 7;
    int hw = ((bid & 127) << 8) | threadIdx.x;
    int h = hw >> 8, w = hw & 255;
    const float* lb = lab + (size_t)b * 18 * NHW + hw;
    const float* rb = reg + (size_t)b * 36 * NHW + hw;
    uint32_t th = thresh[b];
    float acx = (float)(w * 16) + 7.5f;
    float acy = (float)(h * 16) + 7.5f;
#pragma unroll
    for (int a = 0; a < NANCH; ++a) {
        float s  = lb[(2 * a + 1) * NHW];
        float dx = rb[(4 * a + 0) * NHW];
        float dy = rb[(4 * a + 1) * NHW];
        float dwv = rb[(4 * a + 2) * NHW];
        float dhv = rb[(4 * a + 3) * NHW];
        float x1, y1, x2, y2;
        bool keep = decode_clip(dx, dy, dwv, dhv, c_AW[a], c_AH[a], acx, acy, x1, y1, x2, y2);
        float ms = keep ? s : -1e30f;
        uint32_t key = f2key(ms);
        if (key >= th) {
            uint32_t pos = atomicAdd(&cnt[b], 1u);
            if (pos < (uint32_t)CAPN) {
                uint32_t n = (uint32_t)(hw * NANCH + a);
                cand[(size_t)b * CAPN + pos] = ((uint64_t)key << 32) | (uint32_t)(~n);
            }
        }
    }
}

// ---------------- K4: per-batch bitonic sort (descending) of composites ----------------
__global__ __launch_bounds__(1024) void k_sort(const uint32_t* __restrict__ cnt,
                                               const uint64_t* __restrict__ cand,
                                               uint32_t* __restrict__ sel) {
    __shared__ uint64_t sm[CAPN];            // 64 KiB
    int b = blockIdx.x;
    uint32_t C = cnt[b];
    if (C > (uint32_t)CAPN) C = CAPN;
    const uint64_t* cb = cand + (size_t)b * CAPN;
    for (int i = threadIdx.x; i < CAPN; i += 1024) sm[i] = (i < (int)C) ? cb[i] : 0ull;
    __syncthreads();
    for (int k = 2; k <= CAPN; k <<= 1) {
        for (int j = k >> 1; j > 0; j >>= 1) {
            for (int i = threadIdx.x; i < CAPN; i += 1024) {
                int ixj = i ^ j;
                if (ixj > i) {
                    uint64_t va = sm[i], vb = sm[ixj];
                    bool up = ((i & k) == 0);               // descending overall
                    bool sw = up ? (va < vb) : (va > vb);
                    if (sw) { sm[i] = vb; sm[ixj] = va; }
                }
            }
            __syncthreads();
        }
    }
    for (int p = threadIdx.x; p < PRE; p += 1024)
        sel[b * PRE + p] = ~(uint32_t)(sm[p] & 0xFFFFFFFFull);
}

// ---------------- K5: gather/decode selected boxes + raw scores ----------------
__global__ __launch_bounds__(256) void k_gather(const float* __restrict__ lab,
                                                const float* __restrict__ reg,
                                                const uint32_t* __restrict__ sel,
                                                float4* __restrict__ boxes,
                                                float* __restrict__ scores) {
    int g = blockIdx.x * 256 + threadIdx.x;
    if (g >= NBATCH * PRE) return;
    int b = g / PRE, p = g - b * PRE;
    uint32_t n = sel[b * PRE + p];
    if (n >= (uint32_t)NTOT) n = 0;          // pathological guard
    int a = (int)(n % NANCH);
    int hw = (int)(n / NANCH);
    int w = hw & 255, h = hw >> 8;
    const float* lb = lab + (size_t)b * 18 * NHW + hw;
    const float* rb = reg + (size_t)b * 36 * NHW + hw;
    float s  = lb[(2 * a + 1) * NHW];
    float dx = rb[(4 * a + 0) * NHW];
    float dy = rb[(4 * a + 1) * NHW];
    float dwv = rb[(4 * a + 2) * NHW];
    float dhv = rb[(4 * a + 3) * NHW];
    float acx = (float)(w * 16) + 7.5f;
    float acy = (float)(h * 16) + 7.5f;
    float x1, y1, x2, y2;
    decode_clip(dx, dy, dwv, dhv, c_AW[a], c_AH[a], acx, acy, x1, y1, x2, y2);
    boxes[b * PRE + p] = make_float4(x1, y1, x2, y2);
    scores[b * PRE + p] = s;
}

// ---------------- K6: greedy NMS, one block per batch ----------------
__global__ __launch_bounds__(512) void k_nms(const float4* __restrict__ boxes,
                                             const float* __restrict__ scores,
                                             float* __restrict__ out) {
    __shared__ uint64_t alive[NWORDS];
    __shared__ uint32_t sNext;
    int b = blockIdx.x;
    int tid = threadIdx.x;
    const float4* bb = boxes + b * PRE;
    const float* sb = scores + b * PRE;
    if (tid < NWORDS) alive[tid] = (tid == NWORDS - 1) ? ((1ull << 48) - 1ull) : ~0ull;
    __syncthreads();
    uint32_t cur = 0;
    for (int t = 0; t < POST; ++t) {
        if (tid == 0) sNext = 0xFFFFFFFFu;
        __syncthreads();                                     // reset visible
        uint32_t e = (cur < (uint32_t)PRE) ? cur : 0u;
        float4 bc = bb[e];                                    // same addr, broadcast
        if (tid == 0) {
            size_t ob = ((size_t)b * POST + t) * 4;
            out[ob + 0] = bc.x; out[ob + 1] = bc.y;
            out[ob + 2] = bc.z; out[ob + 3] = bc.w;
            out[(size_t)NBATCH * POST * 4 + (size_t)b * POST + t] = sb[e];
            if (cur < (uint32_t)PRE)
                atomicAnd(&alive[cur >> 6], ~(1ull << (cur & 63)));
        }
        if (cur < (uint32_t)PRE) {
            float areaC = __fmul_rn(__fadd_rn(__fsub_rn(bc.z, bc.x), 1.f),
                                    __fadd_rn(__fsub_rn(bc.w, bc.y), 1.f));
            for (uint32_t j = cur + 1 + tid; j < (uint32_t)PRE; j += 512) {
                uint64_t wd = alive[j >> 6];
                if ((wd >> (j & 63)) & 1ull) {
                    float4 bj = bb[j];
                    float xx1 = fmaxf(bc.x, bj.x);
                    float yy1 = fmaxf(bc.y, bj.y);
                    float xx2 = fminf(bc.z, bj.z);
                    float yy2 = fminf(bc.w, bj.w);
                    float iw = fmaxf(__fadd_rn(__fsub_rn(xx2, xx1), 1.f), 0.f);
                    float ih = fmaxf(__fadd_rn(__fsub_rn(yy2, yy1), 1.f), 0.f);
                    float inter = __fmul_rn(iw, ih);
                    float areaJ = __fmul_rn(__fadd_rn(__fsub_rn(bj.z, bj.x), 1.f),
                                            __fadd_rn(__fsub_rn(bj.w, bj.y), 1.f));
                    float iou = __fdiv_rn(inter, __fsub_rn(__fadd_rn(areaC, areaJ), inter));
                    if (iou > 0.7f)
                        atomicAnd(&alive[j >> 6], ~(1ull << (j & 63)));
                }
            }
        }
        __syncthreads();                                     // suppression done
        if (tid < NWORDS) {
            uint64_t wd = alive[tid];
            if (wd) atomicMin(&sNext, (uint32_t)(tid * 64 + (__ffsll((unsigned long long)wd) - 1)));
        }
        __syncthreads();                                     // scan done
        cur = sNext;
        __syncthreads();                                     // everyone read before next reset
    }
}

extern "C" void kernel_launch(void* const* d_in, const int* in_sizes, int n_in,
                              void* d_out, int out_size, void* d_ws, size_t ws_size,
                              hipStream_t stream) {
    (void)in_sizes; (void)n_in; (void)out_size; (void)ws_size;
    const float* lab = (const float*)d_in[0];
    const float* reg = (const float*)d_in[1];
    float* out = (float*)d_out;
    char* ws = (char*)d_ws;

    // workspace layout (bytes)
    uint32_t* ghist  = (uint32_t*)(ws + 0);          // 16*8192*4 = 524288
    uint32_t* cnt    = (uint32_t*)(ws + 524288);     // 64
    uint32_t* thr    = (uint32_t*)(ws + 524352);     // 64
    uint64_t* cand   = (uint64_t*)(ws + 524416);     // 16*8192*8 = 1048576
    uint32_t* sel    = (uint32_t*)(ws + 1572992);    // 16*6000*4 = 384000
    float4*   boxes  = (float4*)  (ws + 1956992);    // 16*6000*16 = 1536000
    float*    scores = (float*)   (ws + 3492992);    // 16*6000*4 = 384000
                                                     // total ~3.7 MB

    hipMemsetAsync(ws, 0, 524416, stream);           // zero ghist + cnt (+thr)

    k_hist   <<<2048, 256, 0, stream>>>(lab, reg, ghist);
    k_thresh <<<NBATCH, 256, 0, stream>>>(ghist, thr);
    k_compact<<<2048, 256, 0, stream>>>(lab, reg, thr, cnt, cand);
    k_sort   <<<NBATCH, 1024, 0, stream>>>(cnt, cand, sel);
    k_gather <<<(NBATCH * PRE + 255) / 256, 256, 0, stream>>>(lab, reg, sel, boxes, scores);
    k_nms    <<<NBATCH, 512, 0, stream>>>(boxes, scores, out);
}

// Round 2
// 1862.565 us; speedup vs baseline: 1.2663x; 1.2663x over previous
//
#include <hip/hip_runtime.h>
#include <stdint.h>

#define NBATCH 16
#define NANCH  9
#define NHGT   128
#define NWID   256
#define NHW    (NHGT * NWID)       // 32768
#define NTOT   (NHW * NANCH)       // 294912
#define PRE    6000
#define POST   300
#define CAPN   8192
#define BINS   8192
#define BIN_SHIFT 19
#define NWORDS 94                  // ceil(6000/64)
#define IOU_BLOCKS_PER_BATCH 25
#define IOU_ROWS_PER_BLOCK   240   // 25*240 = 6000

__device__ __constant__ float c_AW[NANCH] = {184.f,368.f,736.f,128.f,256.f,512.f,88.f,176.f,352.f};
__device__ __constant__ float c_AH[NANCH] = {96.f,192.f,384.f,128.f,256.f,512.f,176.f,352.f,704.f};

__device__ __forceinline__ uint32_t f2key(float f) {
    uint32_t u = __float_as_uint(f);
    return (u & 0x80000000u) ? ~u : (u | 0x80000000u);
}

// decode + clip, mirroring the reference op order; _rn intrinsics forbid fma contraction
__device__ __forceinline__ bool decode_clip(float dx, float dy, float dw, float dh,
                                            float aw, float ah, float acx, float acy,
                                            float& x1, float& y1, float& x2, float& y2) {
    float pcx = __fadd_rn(__fmul_rn(dx, aw), acx);
    float pcy = __fadd_rn(__fmul_rn(dy, ah), acy);
    float pw  = __fmul_rn(expf(dw), aw);
    float ph  = __fmul_rn(expf(dh), ah);
    float hx  = __fmul_rn(0.5f, pw);
    float hy  = __fmul_rn(0.5f, ph);
    x1 = __fsub_rn(pcx, hx);
    y1 = __fsub_rn(pcy, hy);
    x2 = __fadd_rn(pcx, hx);
    y2 = __fadd_rn(pcy, hy);
    x1 = fminf(fmaxf(x1, 0.f), 4095.f);
    x2 = fminf(fmaxf(x2, 0.f), 4095.f);
    y1 = fminf(fmaxf(y1, 0.f), 2047.f);
    y2 = fminf(fmaxf(y2, 0.f), 2047.f);
    float wpl = __fadd_rn(__fsub_rn(x2, x1), 1.f);
    float hpl = __fadd_rn(__fsub_rn(y2, y1), 1.f);
    return (wpl >= 16.f) && (hpl >= 16.f);
}

// ---------------- K1: per-batch histogram of masked-score keys ----------------
__global__ __launch_bounds__(256) void k_hist(const float* __restrict__ lab,
                                              const float* __restrict__ reg,
                                              uint32_t* __restrict__ ghist) {
    __shared__ uint32_t hist[BINS];
    for (int i = threadIdx.x; i < BINS; i += 256) hist[i] = 0;
    __syncthreads();
    int bid = blockIdx.x;
    int b = bid >> 7;                       // 128 blocks per batch
    int hw = ((bid & 127) << 8) | threadIdx.x;
    int h = hw >> 8, w = hw & 255;
    const float* lb = lab + (size_t)b * 18 * NHW + hw;
    const float* rb = reg + (size_t)b * 36 * NHW + hw;
    float acx = (float)(w * 16) + 7.5f;     // exact in fp32
    float acy = (float)(h * 16) + 7.5f;
#pragma unroll
    for (int a = 0; a < NANCH; ++a) {
        float s  = lb[(2 * a + 1) * NHW];
        float dx = rb[(4 * a + 0) * NHW];
        float dy = rb[(4 * a + 1) * NHW];
        float dwv = rb[(4 * a + 2) * NHW];
        float dhv = rb[(4 * a + 3) * NHW];
        float x1, y1, x2, y2;
        bool keep = decode_clip(dx, dy, dwv, dhv, c_AW[a], c_AH[a], acx, acy, x1, y1, x2, y2);
        float ms = keep ? s : -1e30f;
        atomicAdd(&hist[f2key(ms) >> BIN_SHIFT], 1u);
    }
    __syncthreads();
    uint32_t* gh = ghist + b * BINS;
    for (int i = threadIdx.x; i < BINS; i += 256) {
        uint32_t c = hist[i];
        if (c) atomicAdd(&gh[i], c);
    }
}

// ---------------- K2: find threshold bin (cumulative from top >= PRE) ----------------
__global__ __launch_bounds__(256) void k_thresh(const uint32_t* __restrict__ ghist,
                                                uint32_t* __restrict__ thresh) {
    __shared__ uint32_t part[256];
    int b = blockIdx.x;
    const uint32_t* gh = ghist + b * BINS;
    uint32_t s = 0;
    int base = threadIdx.x * 32;
    for (int k = 0; k < 32; ++k) s += gh[base + k];
    part[threadIdx.x] = s;
    __syncthreads();
    if (threadIdx.x == 0) {
        uint32_t cum = 0;
        int tb = 0;
        for (int c = 255; c >= 0; --c) {
            if (cum + part[c] >= (uint32_t)PRE) {
                for (int i = 31; i >= 0; --i) {
                    cum += gh[c * 32 + i];
                    if (cum >= (uint32_t)PRE) { tb = c * 32 + i; break; }
                }
                break;
            }
            cum += part[c];
        }
        thresh[b] = (uint32_t)tb << BIN_SHIFT;
    }
}

// ---------------- K3: recompute keys, compact candidates >= threshold ----------------
__global__ __launch_bounds__(256) void k_compact(const float* __restrict__ lab,
                                                 const float* __restrict__ reg,
                                                 const uint32_t* __restrict__ thresh,
                                                 uint32_t* __restrict__ cnt,
                                                 uint64_t* __restrict__ cand) {
    int bid = blockIdx.x;
    int b = bid >> 7;
    int hw = ((bid & 127) << 8) | threadIdx.x;
    int h = hw >> 8, w = hw & 255;
    const float* lb = lab + (size_t)b * 18 * NHW + hw;
    const float* rb = reg + (size_t)b * 36 * NHW + hw;
    uint32_t th = thresh[b];
    float acx = (float)(w * 16) + 7.5f;
    float acy = (float)(h * 16) + 7.5f;
#pragma unroll
    for (int a = 0; a < NANCH; ++a) {
        float s  = lb[(2 * a + 1) * NHW];
        float dx = rb[(4 * a + 0) * NHW];
        float dy = rb[(4 * a + 1) * NHW];
        float dwv = rb[(4 * a + 2) * NHW];
        float dhv = rb[(4 * a + 3) * NHW];
        float x1, y1, x2, y2;
        bool keep = decode_clip(dx, dy, dwv, dhv, c_AW[a], c_AH[a], acx, acy, x1, y1, x2, y2);
        float ms = keep ? s : -1e30f;
        uint32_t key = f2key(ms);
        if (key >= th) {
            uint32_t pos = atomicAdd(&cnt[b], 1u);
            if (pos < (uint32_t)CAPN) {
                uint32_t n = (uint32_t)(hw * NANCH + a);
                cand[(size_t)b * CAPN + pos] = ((uint64_t)key << 32) | (uint32_t)(~n);
            }
        }
    }
}

// ---------------- K4: per-batch bitonic sort (descending) of composites ----------------
__global__ __launch_bounds__(1024) void k_sort(const uint32_t* __restrict__ cnt,
                                               const uint64_t* __restrict__ cand,
                                               uint32_t* __restrict__ sel) {
    __shared__ uint64_t sm[CAPN];            // 64 KiB
    int b = blockIdx.x;
    uint32_t C = cnt[b];
    if (C > (uint32_t)CAPN) C = CAPN;
    const uint64_t* cb = cand + (size_t)b * CAPN;
    for (int i = threadIdx.x; i < CAPN; i += 1024) sm[i] = (i < (int)C) ? cb[i] : 0ull;
    __syncthreads();
    for (int k = 2; k <= CAPN; k <<= 1) {
        for (int j = k >> 1; j > 0; j >>= 1) {
            for (int i = threadIdx.x; i < CAPN; i += 1024) {
                int ixj = i ^ j;
                if (ixj > i) {
                    uint64_t va = sm[i], vb = sm[ixj];
                    bool up = ((i & k) == 0);               // descending overall
                    bool sw = up ? (va < vb) : (va > vb);
                    if (sw) { sm[i] = vb; sm[ixj] = va; }
                }
            }
            __syncthreads();
        }
    }
    for (int p = threadIdx.x; p < PRE; p += 1024)
        sel[b * PRE + p] = ~(uint32_t)(sm[p] & 0xFFFFFFFFull);
}

// ---------------- K5: gather/decode selected boxes + raw scores ----------------
__global__ __launch_bounds__(256) void k_gather(const float* __restrict__ lab,
                                                const float* __restrict__ reg,
                                                const uint32_t* __restrict__ sel,
                                                float4* __restrict__ boxes,
                                                float* __restrict__ scores) {
    int g = blockIdx.x * 256 + threadIdx.x;
    if (g >= NBATCH * PRE) return;
    int b = g / PRE, p = g - b * PRE;
    uint32_t n = sel[b * PRE + p];
    if (n >= (uint32_t)NTOT) n = 0;          // pathological guard
    int a = (int)(n % NANCH);
    int hw = (int)(n / NANCH);
    int w = hw & 255, h = hw >> 8;
    const float* lb = lab + (size_t)b * 18 * NHW + hw;
    const float* rb = reg + (size_t)b * 36 * NHW + hw;
    float s  = lb[(2 * a + 1) * NHW];
    float dx = rb[(4 * a + 0) * NHW];
    float dy = rb[(4 * a + 1) * NHW];
    float dwv = rb[(4 * a + 2) * NHW];
    float dhv = rb[(4 * a + 3) * NHW];
    float acx = (float)(w * 16) + 7.5f;
    float acy = (float)(h * 16) + 7.5f;
    float x1, y1, x2, y2;
    decode_clip(dx, dy, dwv, dhv, c_AW[a], c_AH[a], acx, acy, x1, y1, x2, y2);
    boxes[b * PRE + p] = make_float4(x1, y1, x2, y2);
    scores[b * PRE + p] = s;
}

// ---------------- K6a: suppression bit-matrix (one wave per row) ----------------
__global__ __launch_bounds__(512) void k_iou(const float4* __restrict__ boxes,
                                             uint64_t* __restrict__ supp) {
    __shared__ float4 lb[PRE];               // 96000 B (gfx950 allows >64KB/WG)
    int b    = blockIdx.x / IOU_BLOCKS_PER_BATCH;
    int rblk = blockIdx.x % IOU_BLOCKS_PER_BATCH;
    const float4* bb = boxes + b * PRE;
    for (int i = threadIdx.x; i < PRE; i += 512) lb[i] = bb[i];
    __syncthreads();
    int wave = threadIdx.x >> 6, lane = threadIdx.x & 63;
    int row0 = rblk * IOU_ROWS_PER_BLOCK;
    for (int r = row0 + wave; r < row0 + IOU_ROWS_PER_BLOCK; r += 8) {
        float4 bi = lb[r];
        float areaI = __fmul_rn(__fadd_rn(__fsub_rn(bi.z, bi.x), 1.f),
                                __fadd_rn(__fsub_rn(bi.w, bi.y), 1.f));
        uint64_t keep0 = 0ull, keep1 = 0ull;  // words w==lane / w==64+lane
        int w0 = r >> 6;                      // only j >= row matters (monotone walk)
        for (int w = w0; w < NWORDS; ++w) {
            int j = (w << 6) | lane;
            bool sup = false;
            if (j < PRE) {
                float4 bj = lb[j];
                float xx1 = fmaxf(bi.x, bj.x);
                float yy1 = fmaxf(bi.y, bj.y);
                float xx2 = fminf(bi.z, bj.z);
                float yy2 = fminf(bi.w, bj.w);
                float iw = fmaxf(__fadd_rn(__fsub_rn(xx2, xx1), 1.f), 0.f);
                float ih = fmaxf(__fadd_rn(__fsub_rn(yy2, yy1), 1.f), 0.f);
                float inter = __fmul_rn(iw, ih);
                float areaJ = __fmul_rn(__fadd_rn(__fsub_rn(bj.z, bj.x), 1.f),
                                        __fadd_rn(__fsub_rn(bj.w, bj.y), 1.f));
                float iou = __fdiv_rn(inter, __fsub_rn(__fadd_rn(areaI, areaJ), inter));
                sup = iou > 0.7f;
            }
            uint64_t m = __ballot(sup);
            if (lane == (w & 63)) { if (w < 64) keep0 = m; else keep1 = m; }
        }
        uint64_t* srow = supp + ((size_t)b * PRE + r) * NWORDS;
        srow[lane] = keep0;                  // words < w0 are 0 => AND no-op
        if (lane < NWORDS - 64) srow[64 + lane] = keep1;
    }
}

// ---------------- K6b: greedy walk, one wave per batch, alive mask in registers ----------------
__global__ __launch_bounds__(64) void k_walk(const float4* __restrict__ boxes,
                                             const float* __restrict__ scores,
                                             const uint64_t* __restrict__ supp,
                                             float* __restrict__ out) {
    int b = blockIdx.x;
    int lane = threadIdx.x;
    const float4* bb = boxes + b * PRE;
    const float* sb = scores + b * PRE;
    uint64_t a0 = ~0ull;                                          // word = lane
    uint64_t a1;                                                  // word = 64+lane
    if (lane < 29)       a1 = ~0ull;
    else if (lane == 29) a1 = (1ull << 48) - 1ull;                // word 93: 48 valid bits
    else                 a1 = 0ull;
    for (int t = 0; t < POST; ++t) {
        unsigned long long mA = __ballot(a0 != 0ull);
        unsigned long long mB = __ballot(a1 != 0ull);
        bool have = (mA | mB) != 0ull;
        int i = 0;
        if (have) {
            int wsel;
            unsigned long long word;
            if (mA) {
                wsel = __ffsll(mA) - 1;
                word = (unsigned long long)__shfl((long long)a0, wsel);
            } else {
                int ls = __ffsll(mB) - 1;
                wsel = 64 + ls;
                word = (unsigned long long)__shfl((long long)a1, ls);
            }
            i = (wsel << 6) + (__ffsll(word) - 1);
        }
        if (lane == 0) {
            float4 bc = bb[i];
            size_t ob = ((size_t)b * POST + t) * 4;
            out[ob + 0] = bc.x; out[ob + 1] = bc.y;
            out[ob + 2] = bc.z; out[ob + 3] = bc.w;
            out[(size_t)NBATCH * POST * 4 + (size_t)b * POST + t] = sb[i];
        }
        if (have) {
            const uint64_t* srow = supp + ((size_t)b * PRE + i) * NWORDS;
            a0 &= ~srow[lane];                                    // clears bit i too (self IoU=1)
            if (lane < NWORDS - 64) a1 &= ~srow[64 + lane];
        }
    }
}

// ---------------- fallback NMS (validated R0) if ws too small for supp matrix ----------------
__global__ __launch_bounds__(512) void k_nms(const float4* __restrict__ boxes,
                                             const float* __restrict__ scores,
                                             float* __restrict__ out) {
    __shared__ uint64_t alive[NWORDS];
    __shared__ uint32_t sNext;
    int b = blockIdx.x;
    int tid = threadIdx.x;
    const float4* bb = boxes + b * PRE;
    const float* sb = scores + b * PRE;
    if (tid < NWORDS) alive[tid] = (tid == NWORDS - 1) ? ((1ull << 48) - 1ull) : ~0ull;
    __syncthreads();
    uint32_t cur = 0;
    for (int t = 0; t < POST; ++t) {
        if (tid == 0) sNext = 0xFFFFFFFFu;
        __syncthreads();
        uint32_t e = (cur < (uint32_t)PRE) ? cur : 0u;
        float4 bc = bb[e];
        if (tid == 0) {
            size_t ob = ((size_t)b * POST + t) * 4;
            out[ob + 0] = bc.x; out[ob + 1] = bc.y;
            out[ob + 2] = bc.z; out[ob + 3] = bc.w;
            out[(size_t)NBATCH * POST * 4 + (size_t)b * POST + t] = sb[e];
            if (cur < (uint32_t)PRE)
                atomicAnd(&alive[cur >> 6], ~(1ull << (cur & 63)));
        }
        if (cur < (uint32_t)PRE) {
            float areaC = __fmul_rn(__fadd_rn(__fsub_rn(bc.z, bc.x), 1.f),
                                    __fadd_rn(__fsub_rn(bc.w, bc.y), 1.f));
            for (uint32_t j = cur + 1 + tid; j < (uint32_t)PRE; j += 512) {
                uint64_t wd = alive[j >> 6];
                if ((wd >> (j & 63)) & 1ull) {
                    float4 bj = bb[j];
                    float xx1 = fmaxf(bc.x, bj.x);
                    float yy1 = fmaxf(bc.y, bj.y);
                    float xx2 = fminf(bc.z, bj.z);
                    float yy2 = fminf(bc.w, bj.w);
                    float iw = fmaxf(__fadd_rn(__fsub_rn(xx2, xx1), 1.f), 0.f);
                    float ih = fmaxf(__fadd_rn(__fsub_rn(yy2, yy1), 1.f), 0.f);
                    float inter = __fmul_rn(iw, ih);
                    float areaJ = __fmul_rn(__fadd_rn(__fsub_rn(bj.z, bj.x), 1.f),
                                            __fadd_rn(__fsub_rn(bj.w, bj.y), 1.f));
                    float iou = __fdiv_rn(inter, __fsub_rn(__fadd_rn(areaC, areaJ), inter));
                    if (iou > 0.7f)
                        atomicAnd(&alive[j >> 6], ~(1ull << (j & 63)));
                }
            }
        }
        __syncthreads();
        if (tid < NWORDS) {
            uint64_t wd = alive[tid];
            if (wd) atomicMin(&sNext, (uint32_t)(tid * 64 + (__ffsll((unsigned long long)wd) - 1)));
        }
        __syncthreads();
        cur = sNext;
        __syncthreads();
    }
}

extern "C" void kernel_launch(void* const* d_in, const int* in_sizes, int n_in,
                              void* d_out, int out_size, void* d_ws, size_t ws_size,
                              hipStream_t stream) {
    (void)in_sizes; (void)n_in; (void)out_size;
    const float* lab = (const float*)d_in[0];
    const float* reg = (const float*)d_in[1];
    float* out = (float*)d_out;
    char* ws = (char*)d_ws;

    // workspace layout (bytes)
    uint32_t* ghist  = (uint32_t*)(ws + 0);          // 16*8192*4 = 524288
    uint32_t* cnt    = (uint32_t*)(ws + 524288);     // 64
    uint32_t* thr    = (uint32_t*)(ws + 524352);     // 64
    uint64_t* cand   = (uint64_t*)(ws + 524416);     // 16*8192*8 -> end 1572992
    uint32_t* sel    = (uint32_t*)(ws + 1572992);    // 16*6000*4 -> end 1956992
    float4*   boxes  = (float4*)  (ws + 1956992);    // 16*6000*16 -> end 3492992
    float*    scores = (float*)   (ws + 3492992);    // 16*6000*4 -> end 3876992
    uint64_t* supp   = (uint64_t*)(ws + 3876992);    // 16*6000*94*8 = 72192000 -> end 76068992
    const size_t NEED_SUPP = 76068992ull;

    hipMemsetAsync(ws, 0, 524416, stream);           // zero ghist + cnt (+thr)

    k_hist   <<<2048, 256, 0, stream>>>(lab, reg, ghist);
    k_thresh <<<NBATCH, 256, 0, stream>>>(ghist, thr);
    k_compact<<<2048, 256, 0, stream>>>(lab, reg, thr, cnt, cand);
    k_sort   <<<NBATCH, 1024, 0, stream>>>(cnt, cand, sel);
    k_gather <<<(NBATCH * PRE + 255) / 256, 256, 0, stream>>>(lab, reg, sel, boxes, scores);
    if (ws_size >= NEED_SUPP) {
        k_iou  <<<NBATCH * IOU_BLOCKS_PER_BATCH, 512, 0, stream>>>(boxes, supp);
        k_walk <<<NBATCH, 64, 0, stream>>>(boxes, scores, supp, out);
    } else {
        k_nms  <<<NBATCH, 512, 0, stream>>>(boxes, scores, out);
    }
}

// Round 3
// 1233.121 us; speedup vs baseline: 1.9127x; 1.5104x over previous
//
#include <hip/hip_runtime.h>
#include <stdint.h>

#define NBATCH 16
#define NANCH  9
#define NHGT   128
#define NWID   256
#define NHW    (NHGT * NWID)       // 32768
#define NTOT   (NHW * NANCH)       // 294912
#define PRE    6000
#define POST   300
#define CAPN   8192
#define BINS   8192
#define BIN_SHIFT 19
#define NWORDS 94                  // ceil(6000/64)
#define RROWS  2048                // suppression-matrix rows (walk fallback beyond)

// exact replacement for (div_rn(inter,uni) > 0.7f):  (double)inter >= (double)uni * M
// M = midpoint(0.7f, nextafterf(0.7f)); tie rounds to even mantissa (0x3F333334) > 0.7f.
#define MIDP 0x1.6666668p-1

__device__ __constant__ float c_AW[NANCH] = {184.f,368.f,736.f,128.f,256.f,512.f,88.f,176.f,352.f};
__device__ __constant__ float c_AH[NANCH] = {96.f,192.f,384.f,128.f,256.f,512.f,176.f,352.f,704.f};

__device__ __forceinline__ uint32_t f2key(float f) {
    uint32_t u = __float_as_uint(f);
    return (u & 0x80000000u) ? ~u : (u | 0x80000000u);
}

__device__ __forceinline__ bool decode_clip(float dx, float dy, float dw, float dh,
                                            float aw, float ah, float acx, float acy,
                                            float& x1, float& y1, float& x2, float& y2) {
    float pcx = __fadd_rn(__fmul_rn(dx, aw), acx);
    float pcy = __fadd_rn(__fmul_rn(dy, ah), acy);
    float pw  = __fmul_rn(expf(dw), aw);
    float ph  = __fmul_rn(expf(dh), ah);
    float hx  = __fmul_rn(0.5f, pw);
    float hy  = __fmul_rn(0.5f, ph);
    x1 = __fsub_rn(pcx, hx);
    y1 = __fsub_rn(pcy, hy);
    x2 = __fadd_rn(pcx, hx);
    y2 = __fadd_rn(pcy, hy);
    x1 = fminf(fmaxf(x1, 0.f), 4095.f);
    x2 = fminf(fmaxf(x2, 0.f), 4095.f);
    y1 = fminf(fmaxf(y1, 0.f), 2047.f);
    y2 = fminf(fmaxf(y2, 0.f), 2047.f);
    float wpl = __fadd_rn(__fsub_rn(x2, x1), 1.f);
    float hpl = __fadd_rn(__fsub_rn(y2, y1), 1.f);
    return (wpl >= 16.f) && (hpl >= 16.f);
}

// ---------------- K1: private dense histograms, NO global atomics ----------------
// grid 256 = (batch, sub); each block owns slice ghist[(b*16+sub)*BINS .. +BINS)
__global__ __launch_bounds__(256) void k_hist(const float* __restrict__ lab,
                                              const float* __restrict__ reg,
                                              uint32_t* __restrict__ ghist) {
    __shared__ uint32_t hist[BINS];
    for (int i = threadIdx.x; i < BINS; i += 256) hist[i] = 0;
    __syncthreads();
    int b = blockIdx.x >> 4, sub = blockIdx.x & 15;
    const float* lb0 = lab + (size_t)b * 18 * NHW;
    const float* rb0 = reg + (size_t)b * 36 * NHW;
    for (int k = 0; k < 8; ++k) {
        int hw = ((sub * 8 + k) << 8) | threadIdx.x;
        int h = hw >> 8, w = hw & 255;
        const float* lb = lb0 + hw;
        const float* rb = rb0 + hw;
        float acx = (float)(w * 16) + 7.5f;
        float acy = (float)(h * 16) + 7.5f;
#pragma unroll
        for (int a = 0; a < NANCH; ++a) {
            float s  = lb[(2 * a + 1) * NHW];
            float dx = rb[(4 * a + 0) * NHW];
            float dy = rb[(4 * a + 1) * NHW];
            float dwv = rb[(4 * a + 2) * NHW];
            float dhv = rb[(4 * a + 3) * NHW];
            float x1, y1, x2, y2;
            bool keep = decode_clip(dx, dy, dwv, dhv, c_AW[a], c_AH[a], acx, acy, x1, y1, x2, y2);
            float ms = keep ? s : -1e30f;
            atomicAdd(&hist[f2key(ms) >> BIN_SHIFT], 1u);
        }
    }
    __syncthreads();
    uint32_t* gh = ghist + ((size_t)(b * 16 + sub) << 13);
    for (int i = threadIdx.x; i < BINS; i += 256) gh[i] = hist[i];
}

// ---------------- K2: sum 16 slices, find threshold bin ----------------
__global__ __launch_bounds__(256) void k_thresh(const uint32_t* __restrict__ ghist,
                                                uint32_t* __restrict__ thresh) {
    __shared__ uint32_t sum[BINS];   // 32 KB
    __shared__ uint32_t part[256];
    int b = blockIdx.x;
    const uint32_t* gh = ghist + ((size_t)(b * 16) << 13);
    for (int i = threadIdx.x; i < BINS; i += 256) {
        uint32_t s = 0;
#pragma unroll
        for (int sb = 0; sb < 16; ++sb) s += gh[(sb << 13) + i];
        sum[i] = s;
    }
    __syncthreads();
    uint32_t p = 0;
    int base = threadIdx.x * 32;
    for (int k = 0; k < 32; ++k) p += sum[base + k];
    part[threadIdx.x] = p;
    __syncthreads();
    if (threadIdx.x == 0) {
        uint32_t cum = 0;
        int tb = 0;
        for (int c = 255; c >= 0; --c) {
            if (cum + part[c] >= (uint32_t)PRE) {
                for (int i = 31; i >= 0; --i) {
                    cum += sum[c * 32 + i];
                    if (cum >= (uint32_t)PRE) { tb = c * 32 + i; break; }
                }
                break;
            }
            cum += part[c];
        }
        thresh[b] = (uint32_t)tb << BIN_SHIFT;
    }
}

// ---------------- K3: compact candidates >= threshold ----------------
__global__ __launch_bounds__(256) void k_compact(const float* __restrict__ lab,
                                                 const float* __restrict__ reg,
                                                 const uint32_t* __restrict__ thresh,
                                                 uint32_t* __restrict__ cnt,
                                                 uint64_t* __restrict__ cand) {
    int bid = blockIdx.x;
    int b = bid >> 7;
    int hw = ((bid & 127) << 8) | threadIdx.x;
    int h = hw >> 8, w = hw & 255;
    const float* lb = lab + (size_t)b * 18 * NHW + hw;
    const float* rb = reg + (size_t)b * 36 * NHW + hw;
    uint32_t th = thresh[b];
    float acx = (float)(w * 16) + 7.5f;
    float acy = (float)(h * 16) + 7.5f;
#pragma unroll
    for (int a = 0; a < NANCH; ++a) {
        float s  = lb[(2 * a + 1) * NHW];
        float dx = rb[(4 * a + 0) * NHW];
        float dy = rb[(4 * a + 1) * NHW];
        float dwv = rb[(4 * a + 2) * NHW];
        float dhv = rb[(4 * a + 3) * NHW];
        float x1, y1, x2, y2;
        bool keep = decode_clip(dx, dy, dwv, dhv, c_AW[a], c_AH[a], acx, acy, x1, y1, x2, y2);
        float ms = keep ? s : -1e30f;
        uint32_t key = f2key(ms);
        if (key >= th) {
            uint32_t pos = atomicAdd(&cnt[b], 1u);
            if (pos < (uint32_t)CAPN) {
                uint32_t n = (uint32_t)(hw * NANCH + a);
                cand[(size_t)b * CAPN + pos] = ((uint64_t)key << 32) | (uint32_t)(~n);
            }
        }
    }
}

// ---------------- K4: per-batch bitonic sort (descending) ----------------
__global__ __launch_bounds__(1024) void k_sort(const uint32_t* __restrict__ cnt,
                                               const uint64_t* __restrict__ cand,
                                               uint32_t* __restrict__ sel) {
    __shared__ uint64_t sm[CAPN];            // 64 KiB
    int b = blockIdx.x;
    uint32_t C = cnt[b];
    if (C > (uint32_t)CAPN) C = CAPN;
    const uint64_t* cb = cand + (size_t)b * CAPN;
    for (int i = threadIdx.x; i < CAPN; i += 1024) sm[i] = (i < (int)C) ? cb[i] : 0ull;
    __syncthreads();
    for (int k = 2; k <= CAPN; k <<= 1) {
        for (int j = k >> 1; j > 0; j >>= 1) {
            for (int i = threadIdx.x; i < CAPN; i += 1024) {
                int ixj = i ^ j;
                if (ixj > i) {
                    uint64_t va = sm[i], vb = sm[ixj];
                    bool up = ((i & k) == 0);
                    bool sw = up ? (va < vb) : (va > vb);
                    if (sw) { sm[i] = vb; sm[ixj] = va; }
                }
            }
            __syncthreads();
        }
    }
    for (int p = threadIdx.x; p < PRE; p += 1024)
        sel[b * PRE + p] = ~(uint32_t)(sm[p] & 0xFFFFFFFFull);
}

// ---------------- K5: gather/decode selected boxes + raw scores ----------------
__global__ __launch_bounds__(256) void k_gather(const float* __restrict__ lab,
                                                const float* __restrict__ reg,
                                                const uint32_t* __restrict__ sel,
                                                float4* __restrict__ boxes,
                                                float* __restrict__ scores) {
    int g = blockIdx.x * 256 + threadIdx.x;
    if (g >= NBATCH * PRE) return;
    int b = g / PRE, p = g - b * PRE;
    uint32_t n = sel[b * PRE + p];
    if (n >= (uint32_t)NTOT) n = 0;
    int a = (int)(n % NANCH);
    int hw = (int)(n / NANCH);
    int w = hw & 255, h = hw >> 8;
    const float* lb = lab + (size_t)b * 18 * NHW + hw;
    const float* rb = reg + (size_t)b * 36 * NHW + hw;
    float s  = lb[(2 * a + 1) * NHW];
    float dx = rb[(4 * a + 0) * NHW];
    float dy = rb[(4 * a + 1) * NHW];
    float dwv = rb[(4 * a + 2) * NHW];
    float dhv = rb[(4 * a + 3) * NHW];
    float acx = (float)(w * 16) + 7.5f;
    float acy = (float)(h * 16) + 7.5f;
    float x1, y1, x2, y2;
    decode_clip(dx, dy, dwv, dhv, c_AW[a], c_AH[a], acx, acy, x1, y1, x2, y2);
    boxes[b * PRE + p] = make_float4(x1, y1, x2, y2);
    scores[b * PRE + p] = s;
}

// ---------------- K6a: suppression bit-matrix, rows 0..RROWS-1, interleaved ----------------
// grid = 16 batches x 16 blocks; block = 512 thr; wave w, iter m -> row rblk + 16*w + 128*m
__global__ __launch_bounds__(512) void k_iou(const float4* __restrict__ boxes,
                                             uint64_t* __restrict__ supp) {
    __shared__ float4 lb[PRE];               // 96000 B
    __shared__ float  la[PRE];               // 24000 B (areas)
    int b    = blockIdx.x >> 4;
    int rblk = blockIdx.x & 15;
    const float4* bb = boxes + b * PRE;
    for (int i = threadIdx.x; i < PRE; i += 512) {
        float4 v = bb[i];
        lb[i] = v;
        la[i] = __fmul_rn(__fadd_rn(__fsub_rn(v.z, v.x), 1.f),
                          __fadd_rn(__fsub_rn(v.w, v.y), 1.f));
    }
    __syncthreads();
    int wave = threadIdx.x >> 6, lane = threadIdx.x & 63;
#pragma unroll 1
    for (int m = 0; m < 16; ++m) {
        int r = rblk + 16 * wave + 128 * m;   // < RROWS, bijective
        float4 bi = lb[r];
        float areaI = la[r];
        uint64_t keep0 = 0ull, keep1 = 0ull;
        int w0 = r >> 6;
        for (int w = w0; w < NWORDS; ++w) {
            int j = (w << 6) | lane;
            bool sup = false;
            if (j < PRE) {
                float4 bj = lb[j];
                float xx1 = fmaxf(bi.x, bj.x);
                float yy1 = fmaxf(bi.y, bj.y);
                float xx2 = fminf(bi.z, bj.z);
                float yy2 = fminf(bi.w, bj.w);
                float iw = fmaxf(__fadd_rn(__fsub_rn(xx2, xx1), 1.f), 0.f);
                float ih = fmaxf(__fadd_rn(__fsub_rn(yy2, yy1), 1.f), 0.f);
                float inter = __fmul_rn(iw, ih);
                float uni = __fsub_rn(__fadd_rn(areaI, la[j]), inter);
                sup = ((double)inter >= (double)uni * MIDP);   // exact == (div_rn > 0.7f)
            }
            uint64_t mball = __ballot(sup);
            if (lane == (w & 63)) { if (w < 64) keep0 = mball; else keep1 = mball; }
        }
        uint64_t* srow = supp + ((size_t)b * RROWS + r) * NWORDS;
        srow[lane] = keep0;
        if (lane < NWORDS - 64) srow[64 + lane] = keep1;
    }
}

// ---------------- K6b: greedy walk; checkpoint to resume-path if row >= RROWS ----------------
__global__ __launch_bounds__(64) void k_walk(const float4* __restrict__ boxes,
                                             const float* __restrict__ scores,
                                             const uint64_t* __restrict__ supp,
                                             uint32_t* __restrict__ flags,
                                             uint32_t* __restrict__ tsave,
                                             uint64_t* __restrict__ aliveSv,
                                             float* __restrict__ out) {
    int b = blockIdx.x;
    int lane = threadIdx.x;
    const float4* bb = boxes + b * PRE;
    const float* sb = scores + b * PRE;
    uint64_t a0 = ~0ull;
    uint64_t a1;
    if (lane < 29)       a1 = ~0ull;
    else if (lane == 29) a1 = (1ull << 48) - 1ull;
    else                 a1 = 0ull;
    int flag = 0;
    for (int t = 0; t < POST; ++t) {
        unsigned long long mA = __ballot(a0 != 0ull);
        unsigned long long mB = __ballot(a1 != 0ull);
        bool have = (mA | mB) != 0ull;
        int i = 0;
        if (have) {
            int wsel;
            unsigned long long word;
            if (mA) {
                wsel = __ffsll(mA) - 1;
                word = (unsigned long long)__shfl((long long)a0, wsel);
            } else {
                int ls = __ffsll(mB) - 1;
                wsel = 64 + ls;
                word = (unsigned long long)__shfl((long long)a1, ls);
            }
            i = (wsel << 6) + (__ffsll(word) - 1);
        }
        if (have && i >= RROWS) {            // row not precomputed: checkpoint
            aliveSv[b * NWORDS + lane] = a0;
            if (lane < NWORDS - 64) aliveSv[b * NWORDS + 64 + lane] = a1;
            if (lane == 0) tsave[b] = (uint32_t)t;
            flag = 1;
            break;
        }
        if (lane == 0) {
            float4 bc = bb[i];
            size_t ob = ((size_t)b * POST + t) * 4;
            out[ob + 0] = bc.x; out[ob + 1] = bc.y;
            out[ob + 2] = bc.z; out[ob + 3] = bc.w;
            out[(size_t)NBATCH * POST * 4 + (size_t)b * POST + t] = sb[i];
        }
        if (have) {
            const uint64_t* srow = supp + ((size_t)b * RROWS + i) * NWORDS;
            a0 &= ~srow[lane];
            if (lane < NWORDS - 64) a1 &= ~srow[64 + lane];
        }
    }
    if (lane == 0) flags[b] = (uint32_t)flag;
}

// ---------------- K6c: rare exact fallback; early-exits when flag==0 ----------------
__global__ __launch_bounds__(512) void k_resume(const float4* __restrict__ boxes,
                                                const float* __restrict__ scores,
                                                const uint32_t* __restrict__ flags,
                                                const uint32_t* __restrict__ tsave,
                                                const uint64_t* __restrict__ aliveSv,
                                                float* __restrict__ out) {
    int b = blockIdx.x;
    if (flags[b] == 0) return;
    __shared__ uint64_t alive[NWORDS];
    __shared__ uint32_t sCur;
    int tid = threadIdx.x;
    const float4* bb = boxes + b * PRE;
    const float* sb = scores + b * PRE;
    if (tid < NWORDS) alive[tid] = aliveSv[b * NWORDS + tid];
    __syncthreads();
    int t0 = (int)tsave[b];
    for (int t = t0; t < POST; ++t) {
        if (tid == 0) sCur = 0xFFFFFFFFu;
        __syncthreads();
        if (tid < NWORDS) {
            uint64_t wd = alive[tid];
            if (wd) atomicMin(&sCur, (uint32_t)(tid * 64 + (__ffsll((unsigned long long)wd) - 1)));
        }
        __syncthreads();
        uint32_t cur = sCur;
        uint32_t e = (cur < (uint32_t)PRE) ? cur : 0u;
        float4 bc = bb[e];
        if (tid == 0) {
            size_t ob = ((size_t)b * POST + t) * 4;
            out[ob + 0] = bc.x; out[ob + 1] = bc.y;
            out[ob + 2] = bc.z; out[ob + 3] = bc.w;
            out[(size_t)NBATCH * POST * 4 + (size_t)b * POST + t] = sb[e];
            if (cur < (uint32_t)PRE)
                atomicAnd(&alive[cur >> 6], ~(1ull << (cur & 63)));
        }
        if (cur < (uint32_t)PRE) {
            float areaC = __fmul_rn(__fadd_rn(__fsub_rn(bc.z, bc.x), 1.f),
                                    __fadd_rn(__fsub_rn(bc.w, bc.y), 1.f));
            for (uint32_t j = cur + 1 + tid; j < (uint32_t)PRE; j += 512) {
                uint64_t wd = alive[j >> 6];
                if ((wd >> (j & 63)) & 1ull) {
                    float4 bj = bb[j];
                    float xx1 = fmaxf(bc.x, bj.x);
                    float yy1 = fmaxf(bc.y, bj.y);
                    float xx2 = fminf(bc.z, bj.z);
                    float yy2 = fminf(bc.w, bj.w);
                    float iw = fmaxf(__fadd_rn(__fsub_rn(xx2, xx1), 1.f), 0.f);
                    float ih = fmaxf(__fadd_rn(__fsub_rn(yy2, yy1), 1.f), 0.f);
                    float inter = __fmul_rn(iw, ih);
                    float areaJ = __fmul_rn(__fadd_rn(__fsub_rn(bj.z, bj.x), 1.f),
                                            __fadd_rn(__fsub_rn(bj.w, bj.y), 1.f));
                    float uni = __fsub_rn(__fadd_rn(areaC, areaJ), inter);
                    if ((double)inter >= (double)uni * MIDP)
                        atomicAnd(&alive[j >> 6], ~(1ull << (j & 63)));
                }
            }
        }
        __syncthreads();
    }
}

extern "C" void kernel_launch(void* const* d_in, const int* in_sizes, int n_in,
                              void* d_out, int out_size, void* d_ws, size_t ws_size,
                              hipStream_t stream) {
    (void)in_sizes; (void)n_in; (void)out_size; (void)ws_size;
    const float* lab = (const float*)d_in[0];
    const float* reg = (const float*)d_in[1];
    float* out = (float*)d_out;
    char* ws = (char*)d_ws;

    // workspace layout (bytes)
    uint32_t* ghist  = (uint32_t*)(ws + 0);          // 16*16*8192*4 = 8388608
    uint32_t* cnt    = (uint32_t*)(ws + 8388608);    // 64
    uint32_t* thr    = (uint32_t*)(ws + 8388672);    // 64
    uint64_t* cand   = (uint64_t*)(ws + 8388736);    // 1048576 -> 9437312
    uint32_t* sel    = (uint32_t*)(ws + 9437312);    // 384000  -> 9821312
    float4*   boxes  = (float4*)  (ws + 9821312);    // 1536000 -> 11357312
    float*    scores = (float*)   (ws + 11357312);   // 384000  -> 11741312
    uint64_t* supp   = (uint64_t*)(ws + 11741312);   // 16*2048*94*8 = 24641536 -> 36382848
    uint32_t* flags  = (uint32_t*)(ws + 36382848);   // 64
    uint32_t* tsave  = (uint32_t*)(ws + 36382912);   // 64
    uint64_t* aliveS = (uint64_t*)(ws + 36382976);   // 16*94*8 = 12032 -> 36395008

    hipMemsetAsync(cnt, 0, 128, stream);             // cnt + thr only

    k_hist   <<<256, 256, 0, stream>>>(lab, reg, ghist);
    k_thresh <<<NBATCH, 256, 0, stream>>>(ghist, thr);
    k_compact<<<2048, 256, 0, stream>>>(lab, reg, thr, cnt, cand);
    k_sort   <<<NBATCH, 1024, 0, stream>>>(cnt, cand, sel);
    k_gather <<<(NBATCH * PRE + 255) / 256, 256, 0, stream>>>(lab, reg, sel, boxes, scores);
    k_iou    <<<256, 512, 0, stream>>>(boxes, supp);
    k_walk   <<<NBATCH, 64, 0, stream>>>(boxes, scores, supp, flags, tsave, aliveS, out);
    k_resume <<<NBATCH, 512, 0, stream>>>(boxes, scores, flags, tsave, aliveS, out);
}

// Round 4
// 637.543 us; speedup vs baseline: 3.6995x; 1.9342x over previous
//
#include <hip/hip_runtime.h>
#include <stdint.h>

#define NBATCH 16
#define NANCH  9
#define NHGT   128
#define NWID   256
#define NHW    (NHGT * NWID)       // 32768
#define NTOT   (NHW * NANCH)       // 294912
#define PRE    6000
#define POST   300
#define CAPN   8192
#define BINS   8192
#define BIN_SHIFT 19
#define NWORDS 94                  // ceil(6000/64)
#define RROWS  2048                // suppression-matrix rows (walk fallback beyond)

// exact replacement for (div_rn(inter,uni) > 0.7f):  (double)inter >= (double)uni * M
// M = midpoint(0.7f, nextafterf(0.7f)); tie rounds to even mantissa (0x3F333334) > 0.7f.
#define MIDP 0x1.6666668p-1

__device__ __constant__ float c_AW[NANCH] = {184.f,368.f,736.f,128.f,256.f,512.f,88.f,176.f,352.f};
__device__ __constant__ float c_AH[NANCH] = {96.f,192.f,384.f,128.f,256.f,512.f,176.f,352.f,704.f};

__device__ __forceinline__ uint32_t f2key(float f) {
    uint32_t u = __float_as_uint(f);
    return (u & 0x80000000u) ? ~u : (u | 0x80000000u);
}

__device__ __forceinline__ bool decode_clip(float dx, float dy, float dw, float dh,
                                            float aw, float ah, float acx, float acy,
                                            float& x1, float& y1, float& x2, float& y2) {
    float pcx = __fadd_rn(__fmul_rn(dx, aw), acx);
    float pcy = __fadd_rn(__fmul_rn(dy, ah), acy);
    float pw  = __fmul_rn(expf(dw), aw);
    float ph  = __fmul_rn(expf(dh), ah);
    float hx  = __fmul_rn(0.5f, pw);
    float hy  = __fmul_rn(0.5f, ph);
    x1 = __fsub_rn(pcx, hx);
    y1 = __fsub_rn(pcy, hy);
    x2 = __fadd_rn(pcx, hx);
    y2 = __fadd_rn(pcy, hy);
    x1 = fminf(fmaxf(x1, 0.f), 4095.f);
    x2 = fminf(fmaxf(x2, 0.f), 4095.f);
    y1 = fminf(fmaxf(y1, 0.f), 2047.f);
    y2 = fminf(fmaxf(y2, 0.f), 2047.f);
    float wpl = __fadd_rn(__fsub_rn(x2, x1), 1.f);
    float hpl = __fadd_rn(__fsub_rn(y2, y1), 1.f);
    return (wpl >= 16.f) && (hpl >= 16.f);
}

// ---------------- K1: LDS histogram, flush with few global atomics ----------------
// grid 256 = (batch, sub); 16 blocks per batch -> only 16 atomics per bin
__global__ __launch_bounds__(256) void k_hist(const float* __restrict__ lab,
                                              const float* __restrict__ reg,
                                              uint32_t* __restrict__ ghist) {
    __shared__ uint32_t hist[BINS];
    for (int i = threadIdx.x; i < BINS; i += 256) hist[i] = 0;
    __syncthreads();
    int b = blockIdx.x >> 4, sub = blockIdx.x & 15;
    const float* lb0 = lab + (size_t)b * 18 * NHW;
    const float* rb0 = reg + (size_t)b * 36 * NHW;
    for (int k = 0; k < 8; ++k) {
        int hw = ((sub * 8 + k) << 8) | threadIdx.x;
        int h = hw >> 8, w = hw & 255;
        const float* lb = lb0 + hw;
        const float* rb = rb0 + hw;
        float acx = (float)(w * 16) + 7.5f;
        float acy = (float)(h * 16) + 7.5f;
#pragma unroll
        for (int a = 0; a < NANCH; ++a) {
            float s  = lb[(2 * a + 1) * NHW];
            float dx = rb[(4 * a + 0) * NHW];
            float dy = rb[(4 * a + 1) * NHW];
            float dwv = rb[(4 * a + 2) * NHW];
            float dhv = rb[(4 * a + 3) * NHW];
            float x1, y1, x2, y2;
            bool keep = decode_clip(dx, dy, dwv, dhv, c_AW[a], c_AH[a], acx, acy, x1, y1, x2, y2);
            float ms = keep ? s : -1e30f;
            atomicAdd(&hist[f2key(ms) >> BIN_SHIFT], 1u);
        }
    }
    __syncthreads();
    uint32_t* gh = ghist + ((size_t)b << 13);
    for (int i = threadIdx.x; i < BINS; i += 256) {
        uint32_t c = hist[i];
        if (c) atomicAdd(&gh[i], c);
    }
}

// ---------------- K2: find threshold bin (cumulative from top >= PRE) ----------------
__global__ __launch_bounds__(256) void k_thresh(const uint32_t* __restrict__ ghist,
                                                uint32_t* __restrict__ thresh) {
    __shared__ uint32_t part[256];
    int b = blockIdx.x;
    const uint32_t* gh = ghist + ((size_t)b << 13);
    uint32_t p = 0;
    int base = threadIdx.x * 32;
    for (int k = 0; k < 32; ++k) p += gh[base + k];
    part[threadIdx.x] = p;
    __syncthreads();
    if (threadIdx.x == 0) {
        uint32_t cum = 0;
        int tb = 0;
        for (int c = 255; c >= 0; --c) {
            if (cum + part[c] >= (uint32_t)PRE) {
                for (int i = 31; i >= 0; --i) {
                    cum += gh[c * 32 + i];
                    if (cum >= (uint32_t)PRE) { tb = c * 32 + i; break; }
                }
                break;
            }
            cum += part[c];
        }
        thresh[b] = (uint32_t)tb << BIN_SHIFT;
    }
}

// ---------------- K3: compact via LDS staging, ONE global atomic per block ----------------
__global__ __launch_bounds__(256) void k_compact(const float* __restrict__ lab,
                                                 const float* __restrict__ reg,
                                                 const uint32_t* __restrict__ thresh,
                                                 uint32_t* __restrict__ cnt,
                                                 uint64_t* __restrict__ cand) {
    __shared__ uint64_t stage[2304];         // 9 * 256 max candidates, 18 KiB
    __shared__ uint32_t sCount;
    __shared__ uint32_t sBase;
    if (threadIdx.x == 0) sCount = 0;
    __syncthreads();
    int bid = blockIdx.x;
    int b = bid >> 7;
    int hw = ((bid & 127) << 8) | threadIdx.x;
    int h = hw >> 8, w = hw & 255;
    int lane = threadIdx.x & 63;
    const float* lb = lab + (size_t)b * 18 * NHW + hw;
    const float* rb = reg + (size_t)b * 36 * NHW + hw;
    uint32_t th = thresh[b];
    float acx = (float)(w * 16) + 7.5f;
    float acy = (float)(h * 16) + 7.5f;
#pragma unroll
    for (int a = 0; a < NANCH; ++a) {
        float s  = lb[(2 * a + 1) * NHW];
        float dx = rb[(4 * a + 0) * NHW];
        float dy = rb[(4 * a + 1) * NHW];
        float dwv = rb[(4 * a + 2) * NHW];
        float dhv = rb[(4 * a + 3) * NHW];
        float x1, y1, x2, y2;
        bool keep = decode_clip(dx, dy, dwv, dhv, c_AW[a], c_AH[a], acx, acy, x1, y1, x2, y2);
        float ms = keep ? s : -1e30f;
        uint32_t key = f2key(ms);
        bool valid = (key >= th);
        uint64_t mask = __ballot(valid);
        if (mask) {
            int leader = __ffsll((unsigned long long)mask) - 1;
            uint32_t wb = 0;
            if (lane == leader) wb = atomicAdd(&sCount, (uint32_t)__popcll(mask));
            wb = (uint32_t)__shfl((int)wb, leader);
            if (valid) {
                int rank = __popcll(mask & ((1ull << lane) - 1ull));
                uint32_t n = (uint32_t)(hw * NANCH + a);
                stage[wb + rank] = ((uint64_t)key << 32) | (uint32_t)(~n);
            }
        }
    }
    __syncthreads();
    if (threadIdx.x == 0) sBase = atomicAdd(&cnt[b], sCount);
    __syncthreads();
    uint32_t total = sCount, base = sBase;
    for (uint32_t i = threadIdx.x; i < total; i += 256) {
        uint32_t pos = base + i;
        if (pos < (uint32_t)CAPN) cand[(size_t)b * CAPN + pos] = stage[i];
    }
}

// ---------------- K4: per-batch bitonic sort (descending) ----------------
__global__ __launch_bounds__(1024) void k_sort(const uint32_t* __restrict__ cnt,
                                               const uint64_t* __restrict__ cand,
                                               uint32_t* __restrict__ sel) {
    __shared__ uint64_t sm[CAPN];            // 64 KiB
    int b = blockIdx.x;
    uint32_t C = cnt[b];
    if (C > (uint32_t)CAPN) C = CAPN;
    const uint64_t* cb = cand + (size_t)b * CAPN;
    for (int i = threadIdx.x; i < CAPN; i += 1024) sm[i] = (i < (int)C) ? cb[i] : 0ull;
    __syncthreads();
    for (int k = 2; k <= CAPN; k <<= 1) {
        for (int j = k >> 1; j > 0; j >>= 1) {
            for (int i = threadIdx.x; i < CAPN; i += 1024) {
                int ixj = i ^ j;
                if (ixj > i) {
                    uint64_t va = sm[i], vb = sm[ixj];
                    bool up = ((i & k) == 0);
                    bool sw = up ? (va < vb) : (va > vb);
                    if (sw) { sm[i] = vb; sm[ixj] = va; }
                }
            }
            __syncthreads();
        }
    }
    for (int p = threadIdx.x; p < PRE; p += 1024)
        sel[b * PRE + p] = ~(uint32_t)(sm[p] & 0xFFFFFFFFull);
}

// ---------------- K5: gather/decode selected boxes + raw scores ----------------
__global__ __launch_bounds__(256) void k_gather(const float* __restrict__ lab,
                                                const float* __restrict__ reg,
                                                const uint32_t* __restrict__ sel,
                                                float4* __restrict__ boxes,
                                                float* __restrict__ scores) {
    int g = blockIdx.x * 256 + threadIdx.x;
    if (g >= NBATCH * PRE) return;
    int b = g / PRE, p = g - b * PRE;
    uint32_t n = sel[b * PRE + p];
    if (n >= (uint32_t)NTOT) n = 0;
    int a = (int)(n % NANCH);
    int hw = (int)(n / NANCH);
    int w = hw & 255, h = hw >> 8;
    const float* lb = lab + (size_t)b * 18 * NHW + hw;
    const float* rb = reg + (size_t)b * 36 * NHW + hw;
    float s  = lb[(2 * a + 1) * NHW];
    float dx = rb[(4 * a + 0) * NHW];
    float dy = rb[(4 * a + 1) * NHW];
    float dwv = rb[(4 * a + 2) * NHW];
    float dhv = rb[(4 * a + 3) * NHW];
    float acx = (float)(w * 16) + 7.5f;
    float acy = (float)(h * 16) + 7.5f;
    float x1, y1, x2, y2;
    decode_clip(dx, dy, dwv, dhv, c_AW[a], c_AH[a], acx, acy, x1, y1, x2, y2);
    boxes[b * PRE + p] = make_float4(x1, y1, x2, y2);
    scores[b * PRE + p] = s;
}

// ---------------- K6a: suppression bit-matrix, rows 0..RROWS-1, interleaved ----------------
__global__ __launch_bounds__(512) void k_iou(const float4* __restrict__ boxes,
                                             uint64_t* __restrict__ supp) {
    __shared__ float4 lb[PRE];               // 96000 B
    __shared__ float  la[PRE];               // 24000 B (areas)
    int b    = blockIdx.x >> 4;
    int rblk = blockIdx.x & 15;
    const float4* bb = boxes + b * PRE;
    for (int i = threadIdx.x; i < PRE; i += 512) {
        float4 v = bb[i];
        lb[i] = v;
        la[i] = __fmul_rn(__fadd_rn(__fsub_rn(v.z, v.x), 1.f),
                          __fadd_rn(__fsub_rn(v.w, v.y), 1.f));
    }
    __syncthreads();
    int wave = threadIdx.x >> 6, lane = threadIdx.x & 63;
#pragma unroll 1
    for (int m = 0; m < 16; ++m) {
        int r = rblk + 16 * wave + 128 * m;   // < RROWS, bijective
        float4 bi = lb[r];
        float areaI = la[r];
        uint64_t keep0 = 0ull, keep1 = 0ull;
        int w0 = r >> 6;
        for (int w = w0; w < NWORDS; ++w) {
            int j = (w << 6) | lane;
            bool sup = false;
            if (j < PRE) {
                float4 bj = lb[j];
                float xx1 = fmaxf(bi.x, bj.x);
                float yy1 = fmaxf(bi.y, bj.y);
                float xx2 = fminf(bi.z, bj.z);
                float yy2 = fminf(bi.w, bj.w);
                float iw = fmaxf(__fadd_rn(__fsub_rn(xx2, xx1), 1.f), 0.f);
                float ih = fmaxf(__fadd_rn(__fsub_rn(yy2, yy1), 1.f), 0.f);
                float inter = __fmul_rn(iw, ih);
                float uni = __fsub_rn(__fadd_rn(areaI, la[j]), inter);
                sup = ((double)inter >= (double)uni * MIDP);   // exact == (div_rn > 0.7f)
            }
            uint64_t mball = __ballot(sup);
            if (lane == (w & 63)) { if (w < 64) keep0 = mball; else keep1 = mball; }
        }
        uint64_t* srow = supp + ((size_t)b * RROWS + r) * NWORDS;
        srow[lane] = keep0;
        if (lane < NWORDS - 64) srow[64 + lane] = keep1;
    }
}

// ---------------- K6b: greedy walk with sequential-row prefetch ----------------
__global__ __launch_bounds__(64) void k_walk(const float4* __restrict__ boxes,
                                             const float* __restrict__ scores,
                                             const uint64_t* __restrict__ supp,
                                             uint32_t* __restrict__ flags,
                                             uint32_t* __restrict__ tsave,
                                             uint64_t* __restrict__ aliveSv,
                                             float* __restrict__ out) {
    int b = blockIdx.x;
    int lane = threadIdx.x;
    const float4* bb = boxes + b * PRE;
    const float* sb = scores + b * PRE;
    const uint64_t* sbase = supp + (size_t)b * RROWS * NWORDS;
    uint64_t a0 = ~0ull;
    uint64_t a1;
    if (lane < 29)       a1 = ~0ull;
    else if (lane == 29) a1 = (1ull << 48) - 1ull;
    else                 a1 = 0ull;
    int flag = 0;
    int prA = -1, prB = -1;
    uint64_t pA0 = 0, pA1 = 0, pB0 = 0, pB1 = 0;
    for (int t = 0; t < POST; ++t) {
        unsigned long long mA = __ballot(a0 != 0ull);
        unsigned long long mB = __ballot(a1 != 0ull);
        bool have = (mA | mB) != 0ull;
        int i = 0;
        if (have) {
            int wsel;
            unsigned long long word;
            if (mA) {
                wsel = __ffsll(mA) - 1;
                word = (unsigned long long)__shfl((long long)a0, wsel);
            } else {
                int ls = __ffsll(mB) - 1;
                wsel = 64 + ls;
                word = (unsigned long long)__shfl((long long)a1, ls);
            }
            i = (wsel << 6) + (__ffsll(word) - 1);
        }
        if (have && i >= RROWS) {            // row not precomputed: checkpoint
            aliveSv[b * NWORDS + lane] = a0;
            if (lane < NWORDS - 64) aliveSv[b * NWORDS + 64 + lane] = a1;
            if (lane == 0) tsave[b] = (uint32_t)t;
            flag = 1;
            break;
        }
        if (lane == 0) {
            float4 bc = bb[i];
            size_t ob = ((size_t)b * POST + t) * 4;
            out[ob + 0] = bc.x; out[ob + 1] = bc.y;
            out[ob + 2] = bc.z; out[ob + 3] = bc.w;
            out[(size_t)NBATCH * POST * 4 + (size_t)b * POST + t] = sb[i];
        }
        uint64_t r0, r1;
        if (i == prA)      { r0 = pA0; r1 = pA1; }
        else if (i == prB) { r0 = pB0; r1 = pB1; }
        else {
            const uint64_t* srow = sbase + (size_t)i * NWORDS;
            r0 = srow[lane];
            r1 = (lane < NWORDS - 64) ? srow[64 + lane] : 0ull;
        }
        // prefetch next two sequential guesses (speculative; valid region clamp)
        {
            int g1 = i + 1; if (g1 >= RROWS) g1 = RROWS - 1;
            int g2 = i + 2; if (g2 >= RROWS) g2 = RROWS - 1;
            const uint64_t* s1 = sbase + (size_t)g1 * NWORDS;
            const uint64_t* s2 = sbase + (size_t)g2 * NWORDS;
            pA0 = s1[lane]; pA1 = (lane < NWORDS - 64) ? s1[64 + lane] : 0ull;
            pB0 = s2[lane]; pB1 = (lane < NWORDS - 64) ? s2[64 + lane] : 0ull;
            prA = g1; prB = g2;
        }
        a0 &= ~r0;                           // harmless when !have (a0 already 0)
        if (lane < NWORDS - 64) a1 &= ~r1;
    }
    if (lane == 0) flags[b] = (uint32_t)flag;
}

// ---------------- K6c: rare exact fallback; early-exits when flag==0 ----------------
__global__ __launch_bounds__(512) void k_resume(const float4* __restrict__ boxes,
                                                const float* __restrict__ scores,
                                                const uint32_t* __restrict__ flags,
                                                const uint32_t* __restrict__ tsave,
                                                const uint64_t* __restrict__ aliveSv,
                                                float* __restrict__ out) {
    int b = blockIdx.x;
    if (flags[b] == 0) return;
    __shared__ uint64_t alive[NWORDS];
    __shared__ uint32_t sCur;
    int tid = threadIdx.x;
    const float4* bb = boxes + b * PRE;
    const float* sb = scores + b * PRE;
    if (tid < NWORDS) alive[tid] = aliveSv[b * NWORDS + tid];
    __syncthreads();
    int t0 = (int)tsave[b];
    for (int t = t0; t < POST; ++t) {
        if (tid == 0) sCur = 0xFFFFFFFFu;
        __syncthreads();
        if (tid < NWORDS) {
            uint64_t wd = alive[tid];
            if (wd) atomicMin(&sCur, (uint32_t)(tid * 64 + (__ffsll((unsigned long long)wd) - 1)));
        }
        __syncthreads();
        uint32_t cur = sCur;
        uint32_t e = (cur < (uint32_t)PRE) ? cur : 0u;
        float4 bc = bb[e];
        if (tid == 0) {
            size_t ob = ((size_t)b * POST + t) * 4;
            out[ob + 0] = bc.x; out[ob + 1] = bc.y;
            out[ob + 2] = bc.z; out[ob + 3] = bc.w;
            out[(size_t)NBATCH * POST * 4 + (size_t)b * POST + t] = sb[e];
            if (cur < (uint32_t)PRE)
                atomicAnd(&alive[cur >> 6], ~(1ull << (cur & 63)));
        }
        if (cur < (uint32_t)PRE) {
            float areaC = __fmul_rn(__fadd_rn(__fsub_rn(bc.z, bc.x), 1.f),
                                    __fadd_rn(__fsub_rn(bc.w, bc.y), 1.f));
            for (uint32_t j = cur + 1 + tid; j < (uint32_t)PRE; j += 512) {
                uint64_t wd = alive[j >> 6];
                if ((wd >> (j & 63)) & 1ull) {
                    float4 bj = bb[j];
                    float xx1 = fmaxf(bc.x, bj.x);
                    float yy1 = fmaxf(bc.y, bj.y);
                    float xx2 = fminf(bc.z, bj.z);
                    float yy2 = fminf(bc.w, bj.w);
                    float iw = fmaxf(__fadd_rn(__fsub_rn(xx2, xx1), 1.f), 0.f);
                    float ih = fmaxf(__fadd_rn(__fsub_rn(yy2, yy1), 1.f), 0.f);
                    float inter = __fmul_rn(iw, ih);
                    float areaJ = __fmul_rn(__fadd_rn(__fsub_rn(bj.z, bj.x), 1.f),
                                            __fadd_rn(__fsub_rn(bj.w, bj.y), 1.f));
                    float uni = __fsub_rn(__fadd_rn(areaC, areaJ), inter);
                    if ((double)inter >= (double)uni * MIDP)
                        atomicAnd(&alive[j >> 6], ~(1ull << (j & 63)));
                }
            }
        }
        __syncthreads();
    }
}

extern "C" void kernel_launch(void* const* d_in, const int* in_sizes, int n_in,
                              void* d_out, int out_size, void* d_ws, size_t ws_size,
                              hipStream_t stream) {
    (void)in_sizes; (void)n_in; (void)out_size; (void)ws_size;
    const float* lab = (const float*)d_in[0];
    const float* reg = (const float*)d_in[1];
    float* out = (float*)d_out;
    char* ws = (char*)d_ws;

    // workspace layout (bytes)
    uint32_t* ghist  = (uint32_t*)(ws + 0);          // 16*8192*4 = 524288
    uint32_t* cnt    = (uint32_t*)(ws + 524288);     // 64
    uint32_t* thr    = (uint32_t*)(ws + 524352);     // 64
    uint64_t* cand   = (uint64_t*)(ws + 524416);     // 1048576 -> 1572992
    uint32_t* sel    = (uint32_t*)(ws + 1572992);    // 384000  -> 1956992
    float4*   boxes  = (float4*)  (ws + 1956992);    // 1536000 -> 3492992
    float*    scores = (float*)   (ws + 3492992);    // 384000  -> 3876992
    uint64_t* supp   = (uint64_t*)(ws + 3876992);    // 16*2048*94*8 = 24641536 -> 28518528
    uint32_t* flags  = (uint32_t*)(ws + 28518528);   // 64
    uint32_t* tsave  = (uint32_t*)(ws + 28518592);   // 64
    uint64_t* aliveS = (uint64_t*)(ws + 28518656);   // 16*94*8 = 12032 -> 28530688

    hipMemsetAsync(ws, 0, 524416, stream);           // zero ghist + cnt + thr

    k_hist   <<<256, 256, 0, stream>>>(lab, reg, ghist);
    k_thresh <<<NBATCH, 256, 0, stream>>>(ghist, thr);
    k_compact<<<2048, 256, 0, stream>>>(lab, reg, thr, cnt, cand);
    k_sort   <<<NBATCH, 1024, 0, stream>>>(cnt, cand, sel);
    k_gather <<<(NBATCH * PRE + 255) / 256, 256, 0, stream>>>(lab, reg, sel, boxes, scores);
    k_iou    <<<256, 512, 0, stream>>>(boxes, supp);
    k_walk   <<<NBATCH, 64, 0, stream>>>(boxes, scores, supp, flags, tsave, aliveS, out);
    k_resume <<<NBATCH, 512, 0, stream>>>(boxes, scores, flags, tsave, aliveS, out);
}

// Round 5
// 598.350 us; speedup vs baseline: 3.9419x; 1.0655x over previous
//
#include <hip/hip_runtime.h>
#include <stdint.h>

#define NBATCH 16
#define NANCH  9
#define NHGT   128
#define NWID   256
#define NHW    (NHGT * NWID)       // 32768
#define NTOT   (NHW * NANCH)       // 294912
#define PRE    6000
#define POST   300
#define CAPN   8192
#define BINS   8192
#define BIN_SHIFT 19
#define NWORDS 94                  // ceil(6000/64)
#define NWSTRIDE 96                // padded row stride (words) -> 768 B, 16B-aligned
#define RROWS  768                 // suppression-matrix rows (exact fallback beyond)

// exact replacement for (div_rn(inter,uni) > 0.7f):  (double)inter >= (double)uni * M
// M = midpoint(0.7f, nextafterf(0.7f)); tie rounds to even mantissa (0x3F333334) > 0.7f.
#define MIDP 0x1.6666668p-1

__device__ __constant__ float c_AW[NANCH] = {184.f,368.f,736.f,128.f,256.f,512.f,88.f,176.f,352.f};
__device__ __constant__ float c_AH[NANCH] = {96.f,192.f,384.f,128.f,256.f,512.f,176.f,352.f,704.f};

__device__ __forceinline__ uint32_t f2key(float f) {
    uint32_t u = __float_as_uint(f);
    return (u & 0x80000000u) ? ~u : (u | 0x80000000u);
}

__device__ __forceinline__ bool decode_clip(float dx, float dy, float dw, float dh,
                                            float aw, float ah, float acx, float acy,
                                            float& x1, float& y1, float& x2, float& y2) {
    float pcx = __fadd_rn(__fmul_rn(dx, aw), acx);
    float pcy = __fadd_rn(__fmul_rn(dy, ah), acy);
    float pw  = __fmul_rn(expf(dw), aw);
    float ph  = __fmul_rn(expf(dh), ah);
    float hx  = __fmul_rn(0.5f, pw);
    float hy  = __fmul_rn(0.5f, ph);
    x1 = __fsub_rn(pcx, hx);
    y1 = __fsub_rn(pcy, hy);
    x2 = __fadd_rn(pcx, hx);
    y2 = __fadd_rn(pcy, hy);
    x1 = fminf(fmaxf(x1, 0.f), 4095.f);
    x2 = fminf(fmaxf(x2, 0.f), 4095.f);
    y1 = fminf(fmaxf(y1, 0.f), 2047.f);
    y2 = fminf(fmaxf(y2, 0.f), 2047.f);
    float wpl = __fadd_rn(__fsub_rn(x2, x1), 1.f);
    float hpl = __fadd_rn(__fsub_rn(y2, y1), 1.f);
    return (wpl >= 16.f) && (hpl >= 16.f);
}

// ---------------- K1: LDS histogram + emit per-anchor key array ----------------
// grid 256 = (batch, sub); 16 blocks per batch -> 16 global atomics per bin
// keys layout: keys[(b*NANCH + a)*NHW + hw]  (coalesced per anchor-plane)
__global__ __launch_bounds__(256) void k_hist(const float* __restrict__ lab,
                                              const float* __restrict__ reg,
                                              uint32_t* __restrict__ ghist,
                                              uint32_t* __restrict__ keys) {
    __shared__ uint32_t hist[BINS];
    for (int i = threadIdx.x; i < BINS; i += 256) hist[i] = 0;
    __syncthreads();
    int b = blockIdx.x >> 4, sub = blockIdx.x & 15;
    const float* lb0 = lab + (size_t)b * 18 * NHW;
    const float* rb0 = reg + (size_t)b * 36 * NHW;
    uint32_t* kb = keys + (size_t)b * NANCH * NHW;
    for (int k = 0; k < 8; ++k) {
        int hw = ((sub * 8 + k) << 8) | threadIdx.x;
        int h = hw >> 8, w = hw & 255;
        const float* lb = lb0 + hw;
        const float* rb = rb0 + hw;
        float acx = (float)(w * 16) + 7.5f;
        float acy = (float)(h * 16) + 7.5f;
#pragma unroll
        for (int a = 0; a < NANCH; ++a) {
            float s  = lb[(2 * a + 1) * NHW];
            float dx = rb[(4 * a + 0) * NHW];
            float dy = rb[(4 * a + 1) * NHW];
            float dwv = rb[(4 * a + 2) * NHW];
            float dhv = rb[(4 * a + 3) * NHW];
            float x1, y1, x2, y2;
            bool keep = decode_clip(dx, dy, dwv, dhv, c_AW[a], c_AH[a], acx, acy, x1, y1, x2, y2);
            float ms = keep ? s : -1e30f;
            uint32_t key = f2key(ms);
            kb[a * NHW + hw] = key;
            atomicAdd(&hist[key >> BIN_SHIFT], 1u);
        }
    }
    __syncthreads();
    uint32_t* gh = ghist + ((size_t)b << 13);
    for (int i = threadIdx.x; i < BINS; i += 256) {
        uint32_t c = hist[i];
        if (c) atomicAdd(&gh[i], c);
    }
}

// ---------------- K2: find threshold bin (cumulative from top >= PRE) ----------------
__global__ __launch_bounds__(256) void k_thresh(const uint32_t* __restrict__ ghist,
                                                uint32_t* __restrict__ thresh) {
    __shared__ uint32_t part[256];
    int b = blockIdx.x;
    const uint32_t* gh = ghist + ((size_t)b << 13);
    uint32_t p = 0;
    int base = threadIdx.x * 32;
    for (int k = 0; k < 32; ++k) p += gh[base + k];
    part[threadIdx.x] = p;
    __syncthreads();
    if (threadIdx.x == 0) {
        uint32_t cum = 0;
        int tb = 0;
        for (int c = 255; c >= 0; --c) {
            if (cum + part[c] >= (uint32_t)PRE) {
                for (int i = 31; i >= 0; --i) {
                    cum += gh[c * 32 + i];
                    if (cum >= (uint32_t)PRE) { tb = c * 32 + i; break; }
                }
                break;
            }
            cum += part[c];
        }
        thresh[b] = (uint32_t)tb << BIN_SHIFT;
    }
}

// ---------------- K3: compact from key array; LDS staging, 1 atomic/block ----------------
__global__ __launch_bounds__(256) void k_compact(const uint32_t* __restrict__ keys,
                                                 const uint32_t* __restrict__ thresh,
                                                 uint32_t* __restrict__ cnt,
                                                 uint64_t* __restrict__ cand) {
    __shared__ uint64_t stage[2304];         // 9 * 256 max candidates, 18 KiB
    __shared__ uint32_t sCount;
    __shared__ uint32_t sBase;
    if (threadIdx.x == 0) sCount = 0;
    __syncthreads();
    int bid = blockIdx.x;
    int b = bid >> 7;
    int hw = ((bid & 127) << 8) | threadIdx.x;
    int lane = threadIdx.x & 63;
    const uint32_t* kb = keys + (size_t)b * NANCH * NHW + hw;
    uint32_t th = thresh[b];
#pragma unroll
    for (int a = 0; a < NANCH; ++a) {
        uint32_t key = kb[a * NHW];
        bool valid = (key >= th);
        uint64_t mask = __ballot(valid);
        if (mask) {
            int leader = __ffsll((unsigned long long)mask) - 1;
            uint32_t wb = 0;
            if (lane == leader) wb = atomicAdd(&sCount, (uint32_t)__popcll(mask));
            wb = (uint32_t)__shfl((int)wb, leader);
            if (valid) {
                int rank = __popcll(mask & ((1ull << lane) - 1ull));
                uint32_t n = (uint32_t)(hw * NANCH + a);
                stage[wb + rank] = ((uint64_t)key << 32) | (uint32_t)(~n);
            }
        }
    }
    __syncthreads();
    if (threadIdx.x == 0) sBase = atomicAdd(&cnt[b], sCount);
    __syncthreads();
    uint32_t total = sCount, base = sBase;
    for (uint32_t i = threadIdx.x; i < total; i += 256) {
        uint32_t pos = base + i;
        if (pos < (uint32_t)CAPN) cand[(size_t)b * CAPN + pos] = stage[i];
    }
}

// ---------------- K4: per-batch bitonic sort + fused gather/decode epilogue ----------------
__global__ __launch_bounds__(1024) void k_sort(const uint32_t* __restrict__ cnt,
                                               const uint64_t* __restrict__ cand,
                                               const float* __restrict__ lab,
                                               const float* __restrict__ reg,
                                               float4* __restrict__ boxes,
                                               float* __restrict__ scores) {
    __shared__ uint64_t sm[CAPN];            // 64 KiB
    int b = blockIdx.x;
    uint32_t C = cnt[b];
    if (C > (uint32_t)CAPN) C = CAPN;
    const uint64_t* cb = cand + (size_t)b * CAPN;
    for (int i = threadIdx.x; i < CAPN; i += 1024) sm[i] = (i < (int)C) ? cb[i] : 0ull;
    __syncthreads();
    for (int k = 2; k <= CAPN; k <<= 1) {
        for (int j = k >> 1; j > 0; j >>= 1) {
            for (int i = threadIdx.x; i < CAPN; i += 1024) {
                int ixj = i ^ j;
                if (ixj > i) {
                    uint64_t va = sm[i], vb = sm[ixj];
                    bool up = ((i & k) == 0);
                    bool sw = up ? (va < vb) : (va > vb);
                    if (sw) { sm[i] = vb; sm[ixj] = va; }
                }
            }
            __syncthreads();
        }
    }
    // fused gather: decode selected boxes + raw scores
    const float* lb0 = lab + (size_t)b * 18 * NHW;
    const float* rb0 = reg + (size_t)b * 36 * NHW;
    for (int p = threadIdx.x; p < PRE; p += 1024) {
        uint32_t n = ~(uint32_t)(sm[p] & 0xFFFFFFFFull);
        if (n >= (uint32_t)NTOT) n = 0;
        int a = (int)(n % NANCH);
        int hw = (int)(n / NANCH);
        int w = hw & 255, h = hw >> 8;
        float s  = lb0[(2 * a + 1) * NHW + hw];
        float dx = rb0[(4 * a + 0) * NHW + hw];
        float dy = rb0[(4 * a + 1) * NHW + hw];
        float dwv = rb0[(4 * a + 2) * NHW + hw];
        float dhv = rb0[(4 * a + 3) * NHW + hw];
        float acx = (float)(w * 16) + 7.5f;
        float acy = (float)(h * 16) + 7.5f;
        float x1, y1, x2, y2;
        decode_clip(dx, dy, dwv, dhv, c_AW[a], c_AH[a], acx, acy, x1, y1, x2, y2);
        boxes[b * PRE + p] = make_float4(x1, y1, x2, y2);
        scores[b * PRE + p] = s;
    }
}

// ---------------- K6a: suppression bit-matrix, rows 0..RROWS-1, interleaved ----------------
// grid = 16 batches x 16 blocks; 8 waves x 6 rows each: r = rblk + 16*wave + 128*m
__global__ __launch_bounds__(512) void k_iou(const float4* __restrict__ boxes,
                                             uint64_t* __restrict__ supp) {
    __shared__ float4 lb[PRE];               // 96000 B
    __shared__ float  la[PRE];               // 24000 B (areas)
    int b    = blockIdx.x >> 4;
    int rblk = blockIdx.x & 15;
    const float4* bb = boxes + b * PRE;
    for (int i = threadIdx.x; i < PRE; i += 512) {
        float4 v = bb[i];
        lb[i] = v;
        la[i] = __fmul_rn(__fadd_rn(__fsub_rn(v.z, v.x), 1.f),
                          __fadd_rn(__fsub_rn(v.w, v.y), 1.f));
    }
    __syncthreads();
    int wave = threadIdx.x >> 6, lane = threadIdx.x & 63;
#pragma unroll 1
    for (int m = 0; m < 6; ++m) {
        int r = rblk + 16 * wave + 128 * m;   // < RROWS, bijective
        float4 bi = lb[r];
        float areaI = la[r];
        uint64_t keep0 = 0ull, keep1 = 0ull;
        int w0 = r >> 6;
        for (int w = w0; w < NWORDS; ++w) {
            int j = (w << 6) | lane;
            bool sup = false;
            if (j < PRE) {
                float4 bj = lb[j];
                float xx1 = fmaxf(bi.x, bj.x);
                float yy1 = fmaxf(bi.y, bj.y);
                float xx2 = fminf(bi.z, bj.z);
                float yy2 = fminf(bi.w, bj.w);
                float iw = fmaxf(__fadd_rn(__fsub_rn(xx2, xx1), 1.f), 0.f);
                float ih = fmaxf(__fadd_rn(__fsub_rn(yy2, yy1), 1.f), 0.f);
                float inter = __fmul_rn(iw, ih);
                float uni = __fsub_rn(__fadd_rn(areaI, la[j]), inter);
                sup = ((double)inter >= (double)uni * MIDP);   // exact == (div_rn > 0.7f)
            }
            uint64_t mball = __ballot(sup);
            if (lane == (w & 63)) { if (w < 64) keep0 = mball; else keep1 = mball; }
        }
        uint64_t* srow = supp + ((size_t)b * RROWS + r) * NWSTRIDE;
        srow[lane] = keep0;                       // words 0..63
        if (lane < 32) srow[64 + lane] = (lane < 30) ? keep1 : 0ull;  // words 64..93 + zero pad 94,95
    }
}

// ---------------- K6b: greedy walk; packed 16B rows + 4-deep sliding prefetch ----------------
__global__ __launch_bounds__(64) void k_walk(const float4* __restrict__ boxes,
                                             const float* __restrict__ scores,
                                             const uint64_t* __restrict__ supp,
                                             uint32_t* __restrict__ flags,
                                             uint32_t* __restrict__ tsave,
                                             uint64_t* __restrict__ aliveSv,
                                             float* __restrict__ out) {
    int b = blockIdx.x;
    int lane = threadIdx.x;
    const float4* bb = boxes + b * PRE;
    const float* sb = scores + b * PRE;
    const uint64_t* sbase = supp + (size_t)b * RROWS * NWSTRIDE;
    // lane l owns words 2l (bits 128l..128l+63) and 2l+1 (bits +64..+127), l<48
    uint64_t v0, v1;
    if (lane < 46)       { v0 = ~0ull; v1 = ~0ull; }
    else if (lane == 46) { v0 = ~0ull; v1 = (1ull << 48) - 1ull; }  // words 92, 93(48 bits)
    else                 { v0 = 0ull;  v1 = 0ull; }
    int flag = 0;
    int g0 = -1000, g1 = -1000, g2 = -1000, g3 = -1000;             // prefetch window rows
    uint64_t u0a=0,u0b=0,u1a=0,u1b=0,u2a=0,u2b=0,u3a=0,u3b=0;
    for (int t = 0; t < POST; ++t) {
        unsigned long long m = __ballot((v0 | v1) != 0ull);
        bool have = m != 0ull;
        int i = 0;
        if (have) {
            int l = __ffsll(m) - 1;
            uint64_t w0 = (uint64_t)__shfl((long long)v0, l);
            uint64_t w1 = (uint64_t)__shfl((long long)v1, l);
            i = (l << 7) + (w0 ? (__ffsll((unsigned long long)w0) - 1)
                               : (64 + __ffsll((unsigned long long)w1) - 1));
        }
        if (have && i >= RROWS) {                 // row not precomputed: checkpoint
            if (2 * lane < NWORDS)     aliveSv[b * NWORDS + 2 * lane] = v0;
            if (2 * lane + 1 < NWORDS) aliveSv[b * NWORDS + 2 * lane + 1] = v1;
            if (lane == 0) tsave[b] = (uint32_t)t;
            flag = 1;
            break;
        }
        if (lane == 0) {
            float4 bc = bb[i];
            size_t ob = ((size_t)b * POST + t) * 4;
            out[ob + 0] = bc.x; out[ob + 1] = bc.y;
            out[ob + 2] = bc.z; out[ob + 3] = bc.w;
            out[(size_t)NBATCH * POST * 4 + (size_t)b * POST + t] = sb[i];
        }
        if (have) {
            // consume row i: prefetch-window hit or direct load
            uint64_t r0 = 0, r1 = 0;
            bool hit = false;
            if (g0 == i) { r0 = u0a; r1 = u0b; hit = true; }
            if (g1 == i) { r0 = u1a; r1 = u1b; hit = true; }
            if (g2 == i) { r0 = u2a; r1 = u2b; hit = true; }
            if (g3 == i) { r0 = u3a; r1 = u3b; hit = true; }
            if (!hit && lane < 48) {
                const ulonglong2* p = (const ulonglong2*)(sbase + (size_t)i * NWSTRIDE);
                ulonglong2 tv = p[lane];
                r0 = tv.x; r1 = tv.y;
            }
            // slide window to rows i+1..i+4 (wave-uniform shift)
            int shift = i + 1 - g0;
            if (shift < 1 || shift > 4) shift = 4;
            if (shift == 1) {
                u0a=u1a; u0b=u1b; u1a=u2a; u1b=u2b; u2a=u3a; u2b=u3b;
            } else if (shift == 2) {
                u0a=u2a; u0b=u2b; u1a=u3a; u1b=u3b;
            } else if (shift == 3) {
                u0a=u3a; u0b=u3b;
            }
            if (shift >= 4) {
                int g = i + 1;
                if (g < RROWS && lane < 48) {
                    ulonglong2 tv = ((const ulonglong2*)(sbase + (size_t)g * NWSTRIDE))[lane];
                    u0a = tv.x; u0b = tv.y;
                } else { u0a = 0; u0b = 0; }
            }
            if (shift >= 3) {
                int g = i + 2;
                if (g < RROWS && lane < 48) {
                    ulonglong2 tv = ((const ulonglong2*)(sbase + (size_t)g * NWSTRIDE))[lane];
                    u1a = tv.x; u1b = tv.y;
                } else { u1a = 0; u1b = 0; }
            }
            if (shift >= 2) {
                int g = i + 3;
                if (g < RROWS && lane < 48) {
                    ulonglong2 tv = ((const ulonglong2*)(sbase + (size_t)g * NWSTRIDE))[lane];
                    u2a = tv.x; u2b = tv.y;
                } else { u2a = 0; u2b = 0; }
            }
            {
                int g = i + 4;
                if (g < RROWS && lane < 48) {
                    ulonglong2 tv = ((const ulonglong2*)(sbase + (size_t)g * NWSTRIDE))[lane];
                    u3a = tv.x; u3b = tv.y;
                } else { u3a = 0; u3b = 0; }
            }
            g0 = i + 1; g1 = i + 2; g2 = i + 3; g3 = i + 4;
            v0 &= ~r0;
            v1 &= ~r1;
        }
    }
    if (lane == 0) flags[b] = (uint32_t)flag;
}

// ---------------- K6c: rare exact fallback; early-exits when flag==0 ----------------
__global__ __launch_bounds__(512) void k_resume(const float4* __restrict__ boxes,
                                                const float* __restrict__ scores,
                                                const uint32_t* __restrict__ flags,
                                                const uint32_t* __restrict__ tsave,
                                                const uint64_t* __restrict__ aliveSv,
                                                float* __restrict__ out) {
    int b = blockIdx.x;
    if (flags[b] == 0) return;
    __shared__ uint64_t alive[NWORDS];
    __shared__ uint32_t sCur;
    int tid = threadIdx.x;
    const float4* bb = boxes + b * PRE;
    const float* sb = scores + b * PRE;
    if (tid < NWORDS) alive[tid] = aliveSv[b * NWORDS + tid];
    __syncthreads();
    int t0 = (int)tsave[b];
    for (int t = t0; t < POST; ++t) {
        if (tid == 0) sCur = 0xFFFFFFFFu;
        __syncthreads();
        if (tid < NWORDS) {
            uint64_t wd = alive[tid];
            if (wd) atomicMin(&sCur, (uint32_t)(tid * 64 + (__ffsll((unsigned long long)wd) - 1)));
        }
        __syncthreads();
        uint32_t cur = sCur;
        uint32_t e = (cur < (uint32_t)PRE) ? cur : 0u;
        float4 bc = bb[e];
        if (tid == 0) {
            size_t ob = ((size_t)b * POST + t) * 4;
            out[ob + 0] = bc.x; out[ob + 1] = bc.y;
            out[ob + 2] = bc.z; out[ob + 3] = bc.w;
            out[(size_t)NBATCH * POST * 4 + (size_t)b * POST + t] = sb[e];
            if (cur < (uint32_t)PRE)
                atomicAnd(&alive[cur >> 6], ~(1ull << (cur & 63)));
        }
        if (cur < (uint32_t)PRE) {
            float areaC = __fmul_rn(__fadd_rn(__fsub_rn(bc.z, bc.x), 1.f),
                                    __fadd_rn(__fsub_rn(bc.w, bc.y), 1.f));
            for (uint32_t j = cur + 1 + tid; j < (uint32_t)PRE; j += 512) {
                uint64_t wd = alive[j >> 6];
                if ((wd >> (j & 63)) & 1ull) {
                    float4 bj = bb[j];
                    float xx1 = fmaxf(bc.x, bj.x);
                    float yy1 = fmaxf(bc.y, bj.y);
                    float xx2 = fminf(bc.z, bj.z);
                    float yy2 = fminf(bc.w, bj.w);
                    float iw = fmaxf(__fadd_rn(__fsub_rn(xx2, xx1), 1.f), 0.f);
                    float ih = fmaxf(__fadd_rn(__fsub_rn(yy2, yy1), 1.f), 0.f);
                    float inter = __fmul_rn(iw, ih);
                    float areaJ = __fmul_rn(__fadd_rn(__fsub_rn(bj.z, bj.x), 1.f),
                                            __fadd_rn(__fsub_rn(bj.w, bj.y), 1.f));
                    float uni = __fsub_rn(__fadd_rn(areaC, areaJ), inter);
                    if ((double)inter >= (double)uni * MIDP)
                        atomicAnd(&alive[j >> 6], ~(1ull << (j & 63)));
                }
            }
        }
        __syncthreads();
    }
}

extern "C" void kernel_launch(void* const* d_in, const int* in_sizes, int n_in,
                              void* d_out, int out_size, void* d_ws, size_t ws_size,
                              hipStream_t stream) {
    (void)in_sizes; (void)n_in; (void)out_size; (void)ws_size;
    const float* lab = (const float*)d_in[0];
    const float* reg = (const float*)d_in[1];
    float* out = (float*)d_out;
    char* ws = (char*)d_ws;

    // workspace layout (bytes)
    uint32_t* ghist  = (uint32_t*)(ws + 0);          // 16*8192*4 = 524288
    uint32_t* cnt    = (uint32_t*)(ws + 524288);     // 64
    uint32_t* thr    = (uint32_t*)(ws + 524352);     // 64
    uint64_t* cand   = (uint64_t*)(ws + 524416);     // 1048576 -> 1572992
    float4*   boxes  = (float4*)  (ws + 1572992);    // 1536000 -> 3108992
    float*    scores = (float*)   (ws + 3108992);    // 384000  -> 3492992
    uint64_t* supp   = (uint64_t*)(ws + 3492992);    // 16*768*96*8 = 9437184 -> 12930176
    uint32_t* flags  = (uint32_t*)(ws + 12930176);   // 64
    uint32_t* tsave  = (uint32_t*)(ws + 12930240);   // 64
    uint64_t* aliveS = (uint64_t*)(ws + 12930304);   // 16*94*8 = 12032 -> 12942336
    uint32_t* keys   = (uint32_t*)(ws + 12942336);   // 16*294912*4 = 18874368 -> 31816704

    hipMemsetAsync(ws, 0, 524416, stream);           // zero ghist + cnt + thr

    k_hist   <<<256, 256, 0, stream>>>(lab, reg, ghist, keys);
    k_thresh <<<NBATCH, 256, 0, stream>>>(ghist, thr);
    k_compact<<<2048, 256, 0, stream>>>(keys, thr, cnt, cand);
    k_sort   <<<NBATCH, 1024, 0, stream>>>(cnt, cand, lab, reg, boxes, scores);
    k_iou    <<<256, 512, 0, stream>>>(boxes, supp);
    k_walk   <<<NBATCH, 64, 0, stream>>>(boxes, scores, supp, flags, tsave, aliveS, out);
    k_resume <<<NBATCH, 512, 0, stream>>>(boxes, scores, flags, tsave, aliveS, out);
}

// Round 7
// 438.627 us; speedup vs baseline: 5.3773x; 1.3641x over previous
//
#include <hip/hip_runtime.h>
#include <stdint.h>

#define NBATCH 16
#define NANCH  9
#define NHGT   128
#define NWID   256
#define NHW    (NHGT * NWID)       // 32768
#define NTOT   (NHW * NANCH)       // 294912
#define PRE    6000
#define POST   300
#define CAPN   8192
#define BINS   8192
#define BIN_SHIFT 19
#define NWORDS 94                  // ceil(6000/64)
#define NWSTRIDE 96                // padded row stride (words) -> 768 B, 16B-aligned
#define RROWS  768                 // suppression-matrix rows (exact fallback beyond)
#define NGROUPS (RROWS / 8)        // 96 groups of 8 rows

// exact replacement for (div_rn(inter,uni) > 0.7f):  (double)inter >= (double)uni * M
// M = midpoint(0.7f, nextafterf(0.7f)); tie rounds to even mantissa (0x3F333334) > 0.7f.
#define MIDP 0x1.6666668p-1

__device__ __constant__ float c_AW[NANCH] = {184.f,368.f,736.f,128.f,256.f,512.f,88.f,176.f,352.f};
__device__ __constant__ float c_AH[NANCH] = {96.f,192.f,384.f,128.f,256.f,512.f,176.f,352.f,704.f};

__device__ __forceinline__ uint32_t f2key(float f) {
    uint32_t u = __float_as_uint(f);
    return (u & 0x80000000u) ? ~u : (u | 0x80000000u);
}

__device__ __forceinline__ bool decode_clip(float dx, float dy, float dw, float dh,
                                            float aw, float ah, float acx, float acy,
                                            float& x1, float& y1, float& x2, float& y2) {
    float pcx = __fadd_rn(__fmul_rn(dx, aw), acx);
    float pcy = __fadd_rn(__fmul_rn(dy, ah), acy);
    float pw  = __fmul_rn(expf(dw), aw);
    float ph  = __fmul_rn(expf(dh), ah);
    float hx  = __fmul_rn(0.5f, pw);
    float hy  = __fmul_rn(0.5f, ph);
    x1 = __fsub_rn(pcx, hx);
    y1 = __fsub_rn(pcy, hy);
    x2 = __fadd_rn(pcx, hx);
    y2 = __fadd_rn(pcy, hy);
    x1 = fminf(fmaxf(x1, 0.f), 4095.f);
    x2 = fminf(fmaxf(x2, 0.f), 4095.f);
    y1 = fminf(fmaxf(y1, 0.f), 2047.f);
    y2 = fminf(fmaxf(y2, 0.f), 2047.f);
    float wpl = __fadd_rn(__fsub_rn(x2, x1), 1.f);
    float hpl = __fadd_rn(__fsub_rn(y2, y1), 1.f);
    return (wpl >= 16.f) && (hpl >= 16.f);
}

// ---------------- K1: LDS histogram + emit per-anchor key array ----------------
__global__ __launch_bounds__(256) void k_hist(const float* __restrict__ lab,
                                              const float* __restrict__ reg,
                                              uint32_t* __restrict__ ghist,
                                              uint32_t* __restrict__ keys) {
    __shared__ uint32_t hist[BINS];
    for (int i = threadIdx.x; i < BINS; i += 256) hist[i] = 0;
    __syncthreads();
    int b = blockIdx.x >> 4, sub = blockIdx.x & 15;
    const float* lb0 = lab + (size_t)b * 18 * NHW;
    const float* rb0 = reg + (size_t)b * 36 * NHW;
    uint32_t* kb = keys + (size_t)b * NANCH * NHW;
    for (int k = 0; k < 8; ++k) {
        int hw = ((sub * 8 + k) << 8) | threadIdx.x;
        int h = hw >> 8, w = hw & 255;
        const float* lb = lb0 + hw;
        const float* rb = rb0 + hw;
        float acx = (float)(w * 16) + 7.5f;
        float acy = (float)(h * 16) + 7.5f;
#pragma unroll
        for (int a = 0; a < NANCH; ++a) {
            float s  = lb[(2 * a + 1) * NHW];
            float dx = rb[(4 * a + 0) * NHW];
            float dy = rb[(4 * a + 1) * NHW];
            float dwv = rb[(4 * a + 2) * NHW];
            float dhv = rb[(4 * a + 3) * NHW];
            float x1, y1, x2, y2;
            bool keep = decode_clip(dx, dy, dwv, dhv, c_AW[a], c_AH[a], acx, acy, x1, y1, x2, y2);
            float ms = keep ? s : -1e30f;
            uint32_t key = f2key(ms);
            kb[a * NHW + hw] = key;
            atomicAdd(&hist[key >> BIN_SHIFT], 1u);
        }
    }
    __syncthreads();
    uint32_t* gh = ghist + ((size_t)b << 13);
    for (int i = threadIdx.x; i < BINS; i += 256) {
        uint32_t c = hist[i];
        if (c) atomicAdd(&gh[i], c);
    }
}

// ---------------- K2: find threshold bin (cumulative from top >= PRE) ----------------
__global__ __launch_bounds__(256) void k_thresh(const uint32_t* __restrict__ ghist,
                                                uint32_t* __restrict__ thresh) {
    __shared__ uint32_t part[256];
    int b = blockIdx.x;
    const uint32_t* gh = ghist + ((size_t)b << 13);
    uint32_t p = 0;
    int base = threadIdx.x * 32;
    for (int k = 0; k < 32; ++k) p += gh[base + k];
    part[threadIdx.x] = p;
    __syncthreads();
    if (threadIdx.x == 0) {
        uint32_t cum = 0;
        int tb = 0;
        for (int c = 255; c >= 0; --c) {
            if (cum + part[c] >= (uint32_t)PRE) {
                for (int i = 31; i >= 0; --i) {
                    cum += gh[c * 32 + i];
                    if (cum >= (uint32_t)PRE) { tb = c * 32 + i; break; }
                }
                break;
            }
            cum += part[c];
        }
        thresh[b] = (uint32_t)tb << BIN_SHIFT;
    }
}

// ---------------- K3: compact from key array; LDS staging, 1 atomic/block ----------------
__global__ __launch_bounds__(256) void k_compact(const uint32_t* __restrict__ keys,
                                                 const uint32_t* __restrict__ thresh,
                                                 uint32_t* __restrict__ cnt,
                                                 uint64_t* __restrict__ cand) {
    __shared__ uint64_t stage[2304];
    __shared__ uint32_t sCount;
    __shared__ uint32_t sBase;
    if (threadIdx.x == 0) sCount = 0;
    __syncthreads();
    int bid = blockIdx.x;
    int b = bid >> 7;
    int hw = ((bid & 127) << 8) | threadIdx.x;
    int lane = threadIdx.x & 63;
    const uint32_t* kb = keys + (size_t)b * NANCH * NHW + hw;
    uint32_t th = thresh[b];
#pragma unroll
    for (int a = 0; a < NANCH; ++a) {
        uint32_t key = kb[a * NHW];
        bool valid = (key >= th);
        uint64_t mask = __ballot(valid);
        if (mask) {
            int leader = __ffsll((unsigned long long)mask) - 1;
            uint32_t wb = 0;
            if (lane == leader) wb = atomicAdd(&sCount, (uint32_t)__popcll(mask));
            wb = (uint32_t)__shfl((int)wb, leader);
            if (valid) {
                int rank = __popcll(mask & ((1ull << lane) - 1ull));
                uint32_t n = (uint32_t)(hw * NANCH + a);
                stage[wb + rank] = ((uint64_t)key << 32) | (uint32_t)(~n);
            }
        }
    }
    __syncthreads();
    if (threadIdx.x == 0) sBase = atomicAdd(&cnt[b], sCount);
    __syncthreads();
    uint32_t total = sCount, base = sBase;
    for (uint32_t i = threadIdx.x; i < total; i += 256) {
        uint32_t pos = base + i;
        if (pos < (uint32_t)CAPN) cand[(size_t)b * CAPN + pos] = stage[i];
    }
}

// ---------------- K4: per-batch bitonic sort + fused gather/decode epilogue ----------------
__global__ __launch_bounds__(1024) void k_sort(const uint32_t* __restrict__ cnt,
                                               const uint64_t* __restrict__ cand,
                                               const float* __restrict__ lab,
                                               const float* __restrict__ reg,
                                               float4* __restrict__ boxes,
                                               float* __restrict__ scores) {
    __shared__ uint64_t sm[CAPN];
    int b = blockIdx.x;
    uint32_t C = cnt[b];
    if (C > (uint32_t)CAPN) C = CAPN;
    const uint64_t* cb = cand + (size_t)b * CAPN;
    for (int i = threadIdx.x; i < CAPN; i += 1024) sm[i] = (i < (int)C) ? cb[i] : 0ull;
    __syncthreads();
    for (int k = 2; k <= CAPN; k <<= 1) {
        for (int j = k >> 1; j > 0; j >>= 1) {
            for (int i = threadIdx.x; i < CAPN; i += 1024) {
                int ixj = i ^ j;
                if (ixj > i) {
                    uint64_t va = sm[i], vb = sm[ixj];
                    bool up = ((i & k) == 0);
                    bool sw = up ? (va < vb) : (va > vb);
                    if (sw) { sm[i] = vb; sm[ixj] = va; }
                }
            }
            __syncthreads();
        }
    }
    const float* lb0 = lab + (size_t)b * 18 * NHW;
    const float* rb0 = reg + (size_t)b * 36 * NHW;
    for (int p = threadIdx.x; p < PRE; p += 1024) {
        uint32_t n = ~(uint32_t)(sm[p] & 0xFFFFFFFFull);
        if (n >= (uint32_t)NTOT) n = 0;
        int a = (int)(n % NANCH);
        int hw = (int)(n / NANCH);
        int w = hw & 255, h = hw >> 8;
        float s  = lb0[(2 * a + 1) * NHW + hw];
        float dx = rb0[(4 * a + 0) * NHW + hw];
        float dy = rb0[(4 * a + 1) * NHW + hw];
        float dwv = rb0[(4 * a + 2) * NHW + hw];
        float dhv = rb0[(4 * a + 3) * NHW + hw];
        float acx = (float)(w * 16) + 7.5f;
        float acy = (float)(h * 16) + 7.5f;
        float x1, y1, x2, y2;
        decode_clip(dx, dy, dwv, dhv, c_AW[a], c_AH[a], acx, acy, x1, y1, x2, y2);
        boxes[b * PRE + p] = make_float4(x1, y1, x2, y2);
        scores[b * PRE + p] = s;
    }
}

// ---------------- K6a: suppression bit-matrix, rows 0..RROWS-1, interleaved ----------------
__global__ __launch_bounds__(512) void k_iou(const float4* __restrict__ boxes,
                                             uint64_t* __restrict__ supp) {
    __shared__ float4 lb[PRE];               // 96000 B
    __shared__ float  la[PRE];               // 24000 B
    int b    = blockIdx.x >> 4;
    int rblk = blockIdx.x & 15;
    const float4* bb = boxes + b * PRE;
    for (int i = threadIdx.x; i < PRE; i += 512) {
        float4 v = bb[i];
        lb[i] = v;
        la[i] = __fmul_rn(__fadd_rn(__fsub_rn(v.z, v.x), 1.f),
                          __fadd_rn(__fsub_rn(v.w, v.y), 1.f));
    }
    __syncthreads();
    int wave = threadIdx.x >> 6, lane = threadIdx.x & 63;
#pragma unroll 1
    for (int m = 0; m < 6; ++m) {
        int r = rblk + 16 * wave + 128 * m;   // < RROWS, bijective
        float4 bi = lb[r];
        float areaI = la[r];
        uint64_t keep0 = 0ull, keep1 = 0ull;
        int w0 = r >> 6;
        for (int w = w0; w < NWORDS; ++w) {
            int j = (w << 6) | lane;
            bool sup = false;
            if (j < PRE) {
                float4 bj = lb[j];
                float xx1 = fmaxf(bi.x, bj.x);
                float yy1 = fmaxf(bi.y, bj.y);
                float xx2 = fminf(bi.z, bj.z);
                float yy2 = fminf(bi.w, bj.w);
                float iw = fmaxf(__fadd_rn(__fsub_rn(xx2, xx1), 1.f), 0.f);
                float ih = fmaxf(__fadd_rn(__fsub_rn(yy2, yy1), 1.f), 0.f);
                float inter = __fmul_rn(iw, ih);
                float uni = __fsub_rn(__fadd_rn(areaI, la[j]), inter);
                sup = ((double)inter >= (double)uni * MIDP);
            }
            uint64_t mball = __ballot(sup);
            if (lane == (w & 63)) { if (w < 64) keep0 = mball; else keep1 = mball; }
        }
        uint64_t* srow = supp + ((size_t)b * RROWS + r) * NWSTRIDE;
        srow[lane] = keep0;
        if (lane < 32) srow[64 + lane] = (lane < 30) ? keep1 : 0ull;
    }
}

// ---------------- K6b: sequential-row walk, triple-buffered static prefetch ----------------
// lane l<48 owns words 2l,2l+1 (bits 128l..128l+127); lane 48 carries box, lane 49 score.
#define SETLOX(V, F) V.x = (uint64_t)__float_as_uint(F)

#define ISSUE(BUF, GRP) do {                                                               \
    int _g = (GRP); if (_g > NGROUPS - 1) _g = NGROUPS - 1;                                \
    int _jb = _g << 3;                                                                     \
    if (lane < 48) {                                                                       \
        const ulonglong2* _p = (const ulonglong2*)(sbase + (size_t)_jb * NWSTRIDE) + lane; \
        BUF##0 = _p[0];   BUF##1 = _p[48];  BUF##2 = _p[96];  BUF##3 = _p[144];            \
        BUF##4 = _p[192]; BUF##5 = _p[240]; BUF##6 = _p[288]; BUF##7 = _p[336];            \
    } else if (lane == 48) {                                                               \
        const ulonglong2* _q = (const ulonglong2*)(bb + _jb);                              \
        BUF##0 = _q[0]; BUF##1 = _q[1]; BUF##2 = _q[2]; BUF##3 = _q[3];                    \
        BUF##4 = _q[4]; BUF##5 = _q[5]; BUF##6 = _q[6]; BUF##7 = _q[7];                    \
    } else if (lane == 49) {                                                               \
        const float* _s = sb + _jb;                                                        \
        SETLOX(BUF##0, _s[0]); SETLOX(BUF##1, _s[1]);                                      \
        SETLOX(BUF##2, _s[2]); SETLOX(BUF##3, _s[3]);                                      \
        SETLOX(BUF##4, _s[4]); SETLOX(BUF##5, _s[5]);                                      \
        SETLOX(BUF##6, _s[6]); SETLOX(BUF##7, _s[7]);                                      \
    }                                                                                      \
} while (0)

#define ROWP(RD, JB, R) {                                                                  \
    if (((curw >> (((JB) & 63) + (R))) & 1ull) != 0ull) {                                  \
        uint64_t _b0 = (uint64_t)__shfl((long long)RD.x, 48);                              \
        uint64_t _b1 = (uint64_t)__shfl((long long)RD.y, 48);                              \
        uint32_t _sc = (uint32_t)(uint64_t)__shfl((long long)RD.x, 49);                    \
        if (lane == 0) {                                                                   \
            size_t _ob = ((size_t)b * POST + t) * 4;                                       \
            out[_ob + 0] = __uint_as_float((uint32_t)_b0);                                 \
            out[_ob + 1] = __uint_as_float((uint32_t)(_b0 >> 32));                         \
            out[_ob + 2] = __uint_as_float((uint32_t)_b1);                                 \
            out[_ob + 3] = __uint_as_float((uint32_t)(_b1 >> 32));                         \
            out[(size_t)NBATCH * POST * 4 + (size_t)b * POST + t] = __uint_as_float(_sc);  \
        }                                                                                  \
        v0 &= ~RD.x; v1 &= ~RD.y;                                                          \
        int _w = ((JB) + (R)) >> 6;                                                        \
        uint64_t _sw = (uint64_t)__shfl((long long)((_w & 1) ? RD.y : RD.x), _w >> 1);     \
        curw &= ~_sw;                                                                      \
        ++t;                                                                               \
        if (t >= POST) goto walk_done;                                                     \
    }                                                                                      \
}

#define PROC(BUF, GRP) do {                                                                \
    int _jb2 = (GRP) << 3;                                                                 \
    if ((_jb2 & 63) == 0) {                                                                \
        int _wi = _jb2 >> 6;                                                               \
        uint64_t _c0 = (uint64_t)__shfl((long long)v0, _wi >> 1);                          \
        uint64_t _c1 = (uint64_t)__shfl((long long)v1, _wi >> 1);                          \
        curw = (_wi & 1) ? _c1 : _c0;                                                      \
    }                                                                                      \
    ROWP(BUF##0, _jb2, 0); ROWP(BUF##1, _jb2, 1); ROWP(BUF##2, _jb2, 2); ROWP(BUF##3, _jb2, 3); \
    ROWP(BUF##4, _jb2, 4); ROWP(BUF##5, _jb2, 5); ROWP(BUF##6, _jb2, 6); ROWP(BUF##7, _jb2, 7); \
} while (0)

__global__ __launch_bounds__(64) void k_walk(const float4* __restrict__ boxes,
                                             const float* __restrict__ scores,
                                             const uint64_t* __restrict__ supp,
                                             uint32_t* __restrict__ flags,
                                             uint32_t* __restrict__ tsave,
                                             uint64_t* __restrict__ aliveSv,
                                             float* __restrict__ out) {
    int b = blockIdx.x;
    int lane = threadIdx.x;
    const float4* bb = boxes + b * PRE;
    const float* sb = scores + b * PRE;
    const uint64_t* sbase = supp + (size_t)b * RROWS * NWSTRIDE;
    uint64_t v0, v1;
    if (lane < 46)       { v0 = ~0ull; v1 = ~0ull; }
    else if (lane == 46) { v0 = ~0ull; v1 = (1ull << 48) - 1ull; }  // words 92, 93(48 bits)
    else                 { v0 = 0ull;  v1 = 0ull; }
    uint64_t curw = 0;
    int t = 0;
    int flag = 0;
    ulonglong2 A0,A1,A2,A3,A4,A5,A6,A7;
    ulonglong2 B0,B1,B2,B3,B4,B5,B6,B7;
    ulonglong2 C0,C1,C2,C3,C4,C5,C6,C7;
    ISSUE(A, 0); ISSUE(B, 1); ISSUE(C, 2);
    for (int g = 0; g < NGROUPS; g += 3) {
        PROC(A, g);     ISSUE(A, g + 3);
        PROC(B, g + 1); ISSUE(B, g + 4);
        PROC(C, g + 2); ISSUE(C, g + 5);
    }
    // t < POST here: either everything below RROWS is dead, or alive bits remain >= RROWS
    {
        unsigned long long anyAlive = __ballot((v0 | v1) != 0ull);
        if (anyAlive == 0ull) {
            // reference semantics: argmax over all-NEG_INF returns 0 -> emit box 0 forever
            if (lane == 0) {
                float4 bc = bb[0];
                float s0 = sb[0];
                for (int tt = t; tt < POST; ++tt) {
                    size_t ob = ((size_t)b * POST + tt) * 4;
                    out[ob + 0] = bc.x; out[ob + 1] = bc.y;
                    out[ob + 2] = bc.z; out[ob + 3] = bc.w;
                    out[(size_t)NBATCH * POST * 4 + (size_t)b * POST + tt] = s0;
                }
            }
        } else {
            // checkpoint for exact serial resume
            if (2 * lane < NWORDS)     aliveSv[b * NWORDS + 2 * lane] = v0;
            if (2 * lane + 1 < NWORDS) aliveSv[b * NWORDS + 2 * lane + 1] = v1;
            if (lane == 0) tsave[b] = (uint32_t)t;
            flag = 1;
        }
    }
walk_done:
    if (lane == 0) flags[b] = (uint32_t)flag;
}

// ---------------- K6c: rare exact fallback; early-exits when flag==0 ----------------
__global__ __launch_bounds__(512) void k_resume(const float4* __restrict__ boxes,
                                                const float* __restrict__ scores,
                                                const uint32_t* __restrict__ flags,
                                                const uint32_t* __restrict__ tsave,
                                                const uint64_t* __restrict__ aliveSv,
                                                float* __restrict__ out) {
    int b = blockIdx.x;
    if (flags[b] == 0) return;
    __shared__ uint64_t alive[NWORDS];
    __shared__ uint32_t sCur;
    int tid = threadIdx.x;
    const float4* bb = boxes + b * PRE;
    const float* sb = scores + b * PRE;
    if (tid < NWORDS) alive[tid] = aliveSv[b * NWORDS + tid];
    __syncthreads();
    int t0 = (int)tsave[b];
    for (int t = t0; t < POST; ++t) {
        if (tid == 0) sCur = 0xFFFFFFFFu;
        __syncthreads();
        if (tid < NWORDS) {
            uint64_t wd = alive[tid];
            if (wd) atomicMin(&sCur, (uint32_t)(tid * 64 + (__ffsll((unsigned long long)wd) - 1)));
        }
        __syncthreads();
        uint32_t cur = sCur;
        uint32_t e = (cur < (uint32_t)PRE) ? cur : 0u;
        float4 bc = bb[e];
        if (tid == 0) {
            size_t ob = ((size_t)b * POST + t) * 4;
            out[ob + 0] = bc.x; out[ob + 1] = bc.y;
            out[ob + 2] = bc.z; out[ob + 3] = bc.w;
            out[(size_t)NBATCH * POST * 4 + (size_t)b * POST + t] = sb[e];
            if (cur < (uint32_t)PRE)
                atomicAnd(&alive[cur >> 6], ~(1ull << (cur & 63)));
        }
        if (cur < (uint32_t)PRE) {
            float areaC = __fmul_rn(__fadd_rn(__fsub_rn(bc.z, bc.x), 1.f),
                                    __fadd_rn(__fsub_rn(bc.w, bc.y), 1.f));
            for (uint32_t j = cur + 1 + tid; j < (uint32_t)PRE; j += 512) {
                uint64_t wd = alive[j >> 6];
                if ((wd >> (j & 63)) & 1ull) {
                    float4 bj = bb[j];
                    float xx1 = fmaxf(bc.x, bj.x);
                    float yy1 = fmaxf(bc.y, bj.y);
                    float xx2 = fminf(bc.z, bj.z);
                    float yy2 = fminf(bc.w, bj.w);
                    float iw = fmaxf(__fadd_rn(__fsub_rn(xx2, xx1), 1.f), 0.f);
                    float ih = fmaxf(__fadd_rn(__fsub_rn(yy2, yy1), 1.f), 0.f);
                    float inter = __fmul_rn(iw, ih);
                    float areaJ = __fmul_rn(__fadd_rn(__fsub_rn(bj.z, bj.x), 1.f),
                                            __fadd_rn(__fsub_rn(bj.w, bj.y), 1.f));
                    float uni = __fsub_rn(__fadd_rn(areaC, areaJ), inter);
                    if ((double)inter >= (double)uni * MIDP)
                        atomicAnd(&alive[j >> 6], ~(1ull << (j & 63)));
                }
            }
        }
        __syncthreads();
    }
}

extern "C" void kernel_launch(void* const* d_in, const int* in_sizes, int n_in,
                              void* d_out, int out_size, void* d_ws, size_t ws_size,
                              hipStream_t stream) {
    (void)in_sizes; (void)n_in; (void)out_size; (void)ws_size;
    const float* lab = (const float*)d_in[0];
    const float* reg = (const float*)d_in[1];
    float* out = (float*)d_out;
    char* ws = (char*)d_ws;

    // workspace layout (bytes)
    uint32_t* ghist  = (uint32_t*)(ws + 0);          // 524288
    uint32_t* cnt    = (uint32_t*)(ws + 524288);     // 64
    uint32_t* thr    = (uint32_t*)(ws + 524352);     // 64
    uint64_t* cand   = (uint64_t*)(ws + 524416);     // -> 1572992
    float4*   boxes  = (float4*)  (ws + 1572992);    // -> 3108992
    float*    scores = (float*)   (ws + 3108992);    // -> 3492992
    uint64_t* supp   = (uint64_t*)(ws + 3492992);    // 16*768*96*8 = 9437184 -> 12930176
    uint32_t* flags  = (uint32_t*)(ws + 12930176);   // 64
    uint32_t* tsave  = (uint32_t*)(ws + 12930240);   // 64
    uint64_t* aliveS = (uint64_t*)(ws + 12930304);   // -> 12942336
    uint32_t* keys   = (uint32_t*)(ws + 12942336);   // -> 31816704

    hipMemsetAsync(ws, 0, 524416, stream);           // zero ghist + cnt + thr

    k_hist   <<<256, 256, 0, stream>>>(lab, reg, ghist, keys);
    k_thresh <<<NBATCH, 256, 0, stream>>>(ghist, thr);
    k_compact<<<2048, 256, 0, stream>>>(keys, thr, cnt, cand);
    k_sort   <<<NBATCH, 1024, 0, stream>>>(cnt, cand, lab, reg, boxes, scores);
    k_iou    <<<256, 512, 0, stream>>>(boxes, supp);
    k_walk   <<<NBATCH, 64, 0, stream>>>(boxes, scores, supp, flags, tsave, aliveS, out);
    k_resume <<<NBATCH, 512, 0, stream>>>(boxes, scores, flags, tsave, aliveS, out);
}

// Round 8
// 395.888 us; speedup vs baseline: 5.9578x; 1.1080x over previous
//
#include <hip/hip_runtime.h>
#include <stdint.h>

#define NBATCH 16
#define NANCH  9
#define NHGT   128
#define NWID   256
#define NHW    (NHGT * NWID)       // 32768
#define NTOT   (NHW * NANCH)       // 294912
#define PRE    6000
#define POST   300
#define CAPN   8192
#define BINS   8192
#define BIN_SHIFT 19
#define NWORDS 94                  // ceil(6000/64)
#define NWSTRIDE 96                // padded row stride (words) -> 768 B, 16B-aligned
#define RROWS  768                 // suppression-matrix rows (exact fallback beyond)
#define NGROUPS (RROWS / 8)        // 96 groups of 8 rows

// exact replacement for (div_rn(inter,uni) > 0.7f):  (double)inter >= (double)uni * M
// M = midpoint(0.7f, nextafterf(0.7f)); tie rounds to even mantissa (0x3F333334) > 0.7f.
#define MIDP 0x1.6666668p-1

__device__ __constant__ float c_AW[NANCH] = {184.f,368.f,736.f,128.f,256.f,512.f,88.f,176.f,352.f};
__device__ __constant__ float c_AH[NANCH] = {96.f,192.f,384.f,128.f,256.f,512.f,176.f,352.f,704.f};

__device__ __forceinline__ uint32_t f2key(float f) {
    uint32_t u = __float_as_uint(f);
    return (u & 0x80000000u) ? ~u : (u | 0x80000000u);
}

__device__ __forceinline__ bool decode_clip(float dx, float dy, float dw, float dh,
                                            float aw, float ah, float acx, float acy,
                                            float& x1, float& y1, float& x2, float& y2) {
    float pcx = __fadd_rn(__fmul_rn(dx, aw), acx);
    float pcy = __fadd_rn(__fmul_rn(dy, ah), acy);
    float pw  = __fmul_rn(expf(dw), aw);
    float ph  = __fmul_rn(expf(dh), ah);
    float hx  = __fmul_rn(0.5f, pw);
    float hy  = __fmul_rn(0.5f, ph);
    x1 = __fsub_rn(pcx, hx);
    y1 = __fsub_rn(pcy, hy);
    x2 = __fadd_rn(pcx, hx);
    y2 = __fadd_rn(pcy, hy);
    x1 = fminf(fmaxf(x1, 0.f), 4095.f);
    x2 = fminf(fmaxf(x2, 0.f), 4095.f);
    y1 = fminf(fmaxf(y1, 0.f), 2047.f);
    y2 = fminf(fmaxf(y2, 0.f), 2047.f);
    float wpl = __fadd_rn(__fsub_rn(x2, x1), 1.f);
    float hpl = __fadd_rn(__fsub_rn(y2, y1), 1.f);
    return (wpl >= 16.f) && (hpl >= 16.f);
}

// ---------------- K1: LDS histogram + emit per-anchor key array ----------------
__global__ __launch_bounds__(256) void k_hist(const float* __restrict__ lab,
                                              const float* __restrict__ reg,
                                              uint32_t* __restrict__ ghist,
                                              uint32_t* __restrict__ keys) {
    __shared__ uint32_t hist[BINS];
    for (int i = threadIdx.x; i < BINS; i += 256) hist[i] = 0;
    __syncthreads();
    int b = blockIdx.x >> 4, sub = blockIdx.x & 15;
    const float* lb0 = lab + (size_t)b * 18 * NHW;
    const float* rb0 = reg + (size_t)b * 36 * NHW;
    uint32_t* kb = keys + (size_t)b * NANCH * NHW;
    for (int k = 0; k < 8; ++k) {
        int hw = ((sub * 8 + k) << 8) | threadIdx.x;
        int h = hw >> 8, w = hw & 255;
        const float* lb = lb0 + hw;
        const float* rb = rb0 + hw;
        float acx = (float)(w * 16) + 7.5f;
        float acy = (float)(h * 16) + 7.5f;
#pragma unroll
        for (int a = 0; a < NANCH; ++a) {
            float s  = lb[(2 * a + 1) * NHW];
            float dx = rb[(4 * a + 0) * NHW];
            float dy = rb[(4 * a + 1) * NHW];
            float dwv = rb[(4 * a + 2) * NHW];
            float dhv = rb[(4 * a + 3) * NHW];
            float x1, y1, x2, y2;
            bool keep = decode_clip(dx, dy, dwv, dhv, c_AW[a], c_AH[a], acx, acy, x1, y1, x2, y2);
            float ms = keep ? s : -1e30f;
            uint32_t key = f2key(ms);
            kb[a * NHW + hw] = key;
            atomicAdd(&hist[key >> BIN_SHIFT], 1u);
        }
    }
    __syncthreads();
    uint32_t* gh = ghist + ((size_t)b << 13);
    for (int i = threadIdx.x; i < BINS; i += 256) {
        uint32_t c = hist[i];
        if (c) atomicAdd(&gh[i], c);
    }
}

// ---------------- K2: find threshold bin (cumulative from top >= PRE) ----------------
__global__ __launch_bounds__(256) void k_thresh(const uint32_t* __restrict__ ghist,
                                                uint32_t* __restrict__ thresh) {
    __shared__ uint32_t part[256];
    int b = blockIdx.x;
    const uint32_t* gh = ghist + ((size_t)b << 13);
    uint32_t p = 0;
    int base = threadIdx.x * 32;
    for (int k = 0; k < 32; ++k) p += gh[base + k];
    part[threadIdx.x] = p;
    __syncthreads();
    if (threadIdx.x == 0) {
        uint32_t cum = 0;
        int tb = 0;
        for (int c = 255; c >= 0; --c) {
            if (cum + part[c] >= (uint32_t)PRE) {
                for (int i = 31; i >= 0; --i) {
                    cum += gh[c * 32 + i];
                    if (cum >= (uint32_t)PRE) { tb = c * 32 + i; break; }
                }
                break;
            }
            cum += part[c];
        }
        thresh[b] = (uint32_t)tb << BIN_SHIFT;
    }
}

// ---------------- K3: compact from key array; LDS staging, 1 atomic/block ----------------
__global__ __launch_bounds__(256) void k_compact(const uint32_t* __restrict__ keys,
                                                 const uint32_t* __restrict__ thresh,
                                                 uint32_t* __restrict__ cnt,
                                                 uint64_t* __restrict__ cand) {
    __shared__ uint64_t stage[2304];
    __shared__ uint32_t sCount;
    __shared__ uint32_t sBase;
    if (threadIdx.x == 0) sCount = 0;
    __syncthreads();
    int bid = blockIdx.x;
    int b = bid >> 7;
    int hw = ((bid & 127) << 8) | threadIdx.x;
    int lane = threadIdx.x & 63;
    const uint32_t* kb = keys + (size_t)b * NANCH * NHW + hw;
    uint32_t th = thresh[b];
#pragma unroll
    for (int a = 0; a < NANCH; ++a) {
        uint32_t key = kb[a * NHW];
        bool valid = (key >= th);
        uint64_t mask = __ballot(valid);
        if (mask) {
            int leader = __ffsll((unsigned long long)mask) - 1;
            uint32_t wb = 0;
            if (lane == leader) wb = atomicAdd(&sCount, (uint32_t)__popcll(mask));
            wb = (uint32_t)__shfl((int)wb, leader);
            if (valid) {
                int rank = __popcll(mask & ((1ull << lane) - 1ull));
                uint32_t n = (uint32_t)(hw * NANCH + a);
                stage[wb + rank] = ((uint64_t)key << 32) | (uint32_t)(~n);
            }
        }
    }
    __syncthreads();
    if (threadIdx.x == 0) sBase = atomicAdd(&cnt[b], sCount);
    __syncthreads();
    uint32_t total = sCount, base = sBase;
    for (uint32_t i = threadIdx.x; i < total; i += 256) {
        uint32_t pos = base + i;
        if (pos < (uint32_t)CAPN) cand[(size_t)b * CAPN + pos] = stage[i];
    }
}

// ---------------- K4a: bitonic phases k=2..1024 within each 1024-chunk ----------------
// grid = 16 batches x 8 chunks = 128 blocks, 256 threads; same canonical network
__global__ __launch_bounds__(256) void k_sort1(const uint32_t* __restrict__ cnt,
                                               uint64_t* __restrict__ cand) {
    __shared__ uint64_t sm[1024];
    int b = blockIdx.x >> 3, c = blockIdx.x & 7;
    uint32_t C = cnt[b];
    if (C > (uint32_t)CAPN) C = CAPN;
    uint64_t* cb = cand + (size_t)b * CAPN;
    int base = c << 10;
    for (int li = threadIdx.x; li < 1024; li += 256) {
        int gi = base + li;
        sm[li] = (gi < (int)C) ? cb[gi] : 0ull;
    }
    __syncthreads();
    for (int k = 2; k <= 1024; k <<= 1) {
        for (int j = k >> 1; j > 0; j >>= 1) {
            for (int li = threadIdx.x; li < 1024; li += 256) {
                int lxj = li ^ j;
                if (lxj > li) {
                    int gi = base + li;                       // global index for direction
                    uint64_t va = sm[li], vb = sm[lxj];
                    bool up = ((gi & k) == 0);
                    bool sw = up ? (va < vb) : (va > vb);
                    if (sw) { sm[li] = vb; sm[lxj] = va; }
                }
            }
            __syncthreads();
        }
    }
    for (int li = threadIdx.x; li < 1024; li += 256) cb[base + li] = sm[li];
}

// ---------------- K4b: merge phases k=2048..8192 + fused gather/decode ----------------
__global__ __launch_bounds__(1024) void k_sort2(const uint64_t* __restrict__ cand,
                                                const float* __restrict__ lab,
                                                const float* __restrict__ reg,
                                                float4* __restrict__ boxes,
                                                float* __restrict__ scores) {
    __shared__ uint64_t sm[CAPN];
    int b = blockIdx.x;
    const uint64_t* cb = cand + (size_t)b * CAPN;
    for (int i = threadIdx.x; i < CAPN; i += 1024) sm[i] = cb[i];
    __syncthreads();
    for (int k = 2048; k <= CAPN; k <<= 1) {
        for (int j = k >> 1; j > 0; j >>= 1) {
            for (int i = threadIdx.x; i < CAPN; i += 1024) {
                int ixj = i ^ j;
                if (ixj > i) {
                    uint64_t va = sm[i], vb = sm[ixj];
                    bool up = ((i & k) == 0);
                    bool sw = up ? (va < vb) : (va > vb);
                    if (sw) { sm[i] = vb; sm[ixj] = va; }
                }
            }
            __syncthreads();
        }
    }
    const float* lb0 = lab + (size_t)b * 18 * NHW;
    const float* rb0 = reg + (size_t)b * 36 * NHW;
    for (int p = threadIdx.x; p < PRE; p += 1024) {
        uint32_t n = ~(uint32_t)(sm[p] & 0xFFFFFFFFull);
        if (n >= (uint32_t)NTOT) n = 0;
        int a = (int)(n % NANCH);
        int hw = (int)(n / NANCH);
        int w = hw & 255, h = hw >> 8;
        float s  = lb0[(2 * a + 1) * NHW + hw];
        float dx = rb0[(4 * a + 0) * NHW + hw];
        float dy = rb0[(4 * a + 1) * NHW + hw];
        float dwv = rb0[(4 * a + 2) * NHW + hw];
        float dhv = rb0[(4 * a + 3) * NHW + hw];
        float acx = (float)(w * 16) + 7.5f;
        float acy = (float)(h * 16) + 7.5f;
        float x1, y1, x2, y2;
        decode_clip(dx, dy, dwv, dhv, c_AW[a], c_AH[a], acx, acy, x1, y1, x2, y2);
        boxes[b * PRE + p] = make_float4(x1, y1, x2, y2);
        scores[b * PRE + p] = s;
    }
}

// ---------------- K6a: suppression bit-matrix, rows 0..RROWS-1, interleaved ----------------
__global__ __launch_bounds__(512) void k_iou(const float4* __restrict__ boxes,
                                             uint64_t* __restrict__ supp) {
    __shared__ float4 lb[PRE];               // 96000 B
    __shared__ float  la[PRE];               // 24000 B
    int b    = blockIdx.x >> 4;
    int rblk = blockIdx.x & 15;
    const float4* bb = boxes + b * PRE;
    for (int i = threadIdx.x; i < PRE; i += 512) {
        float4 v = bb[i];
        lb[i] = v;
        la[i] = __fmul_rn(__fadd_rn(__fsub_rn(v.z, v.x), 1.f),
                          __fadd_rn(__fsub_rn(v.w, v.y), 1.f));
    }
    __syncthreads();
    int wave = threadIdx.x >> 6, lane = threadIdx.x & 63;
#pragma unroll 1
    for (int m = 0; m < 6; ++m) {
        int r = rblk + 16 * wave + 128 * m;   // < RROWS, bijective
        float4 bi = lb[r];
        float areaI = la[r];
        uint64_t keep0 = 0ull, keep1 = 0ull;
        int w0 = r >> 6;
        for (int w = w0; w < NWORDS; ++w) {
            int j = (w << 6) | lane;
            bool sup = false;
            if (j < PRE) {
                float4 bj = lb[j];
                float xx1 = fmaxf(bi.x, bj.x);
                float yy1 = fmaxf(bi.y, bj.y);
                float xx2 = fminf(bi.z, bj.z);
                float yy2 = fminf(bi.w, bj.w);
                float iw = fmaxf(__fadd_rn(__fsub_rn(xx2, xx1), 1.f), 0.f);
                float ih = fmaxf(__fadd_rn(__fsub_rn(yy2, yy1), 1.f), 0.f);
                float inter = __fmul_rn(iw, ih);
                float uni = __fsub_rn(__fadd_rn(areaI, la[j]), inter);
                sup = ((double)inter >= (double)uni * MIDP);
            }
            uint64_t mball = __ballot(sup);
            if (lane == (w & 63)) { if (w < 64) keep0 = mball; else keep1 = mball; }
        }
        uint64_t* srow = supp + ((size_t)b * RROWS + r) * NWSTRIDE;
        srow[lane] = keep0;
        if (lane < 32) srow[64 + lane] = (lane < 30) ? keep1 : 0ull;
    }
}

// ---------------- K6b: sequential-row walk, triple-buffered static prefetch ----------------
// lane l<48 owns words 2l,2l+1 (bits 128l..128l+127); lane 48 carries box, lane 49 score.
#define SETLOX(V, F) V.x = (uint64_t)__float_as_uint(F)

#define ISSUE(BUF, GRP) do {                                                               \
    int _g = (GRP); if (_g > NGROUPS - 1) _g = NGROUPS - 1;                                \
    int _jb = _g << 3;                                                                     \
    if (lane < 48) {                                                                       \
        const ulonglong2* _p = (const ulonglong2*)(sbase + (size_t)_jb * NWSTRIDE) + lane; \
        BUF##0 = _p[0];   BUF##1 = _p[48];  BUF##2 = _p[96];  BUF##3 = _p[144];            \
        BUF##4 = _p[192]; BUF##5 = _p[240]; BUF##6 = _p[288]; BUF##7 = _p[336];            \
    } else if (lane == 48) {                                                               \
        const ulonglong2* _q = (const ulonglong2*)(bb + _jb);                              \
        BUF##0 = _q[0]; BUF##1 = _q[1]; BUF##2 = _q[2]; BUF##3 = _q[3];                    \
        BUF##4 = _q[4]; BUF##5 = _q[5]; BUF##6 = _q[6]; BUF##7 = _q[7];                    \
    } else if (lane == 49) {                                                               \
        const float* _s = sb + _jb;                                                        \
        SETLOX(BUF##0, _s[0]); SETLOX(BUF##1, _s[1]);                                      \
        SETLOX(BUF##2, _s[2]); SETLOX(BUF##3, _s[3]);                                      \
        SETLOX(BUF##4, _s[4]); SETLOX(BUF##5, _s[5]);                                      \
        SETLOX(BUF##6, _s[6]); SETLOX(BUF##7, _s[7]);                                      \
    }                                                                                      \
} while (0)

#define ROWP(RD, JB, R) {                                                                  \
    if (((curw >> (((JB) & 63) + (R))) & 1ull) != 0ull) {                                  \
        uint64_t _b0 = (uint64_t)__shfl((long long)RD.x, 48);                              \
        uint64_t _b1 = (uint64_t)__shfl((long long)RD.y, 48);                              \
        uint32_t _sc = (uint32_t)(uint64_t)__shfl((long long)RD.x, 49);                    \
        if (lane == 0) {                                                                   \
            size_t _ob = ((size_t)b * POST + t) * 4;                                       \
            out[_ob + 0] = __uint_as_float((uint32_t)_b0);                                 \
            out[_ob + 1] = __uint_as_float((uint32_t)(_b0 >> 32));                         \
            out[_ob + 2] = __uint_as_float((uint32_t)_b1);                                 \
            out[_ob + 3] = __uint_as_float((uint32_t)(_b1 >> 32));                         \
            out[(size_t)NBATCH * POST * 4 + (size_t)b * POST + t] = __uint_as_float(_sc);  \
        }                                                                                  \
        v0 &= ~RD.x; v1 &= ~RD.y;                                                          \
        int _w = ((JB) + (R)) >> 6;                                                        \
        uint64_t _sw = (uint64_t)__shfl((long long)((_w & 1) ? RD.y : RD.x), _w >> 1);     \
        curw &= ~_sw;                                                                      \
        ++t;                                                                               \
        if (t >= POST) goto walk_done;                                                     \
    }                                                                                      \
}

#define PROC(BUF, GRP) do {                                                                \
    int _jb2 = (GRP) << 3;                                                                 \
    if ((_jb2 & 63) == 0) {                                                                \
        int _wi = _jb2 >> 6;                                                               \
        uint64_t _c0 = (uint64_t)__shfl((long long)v0, _wi >> 1);                          \
        uint64_t _c1 = (uint64_t)__shfl((long long)v1, _wi >> 1);                          \
        curw = (_wi & 1) ? _c1 : _c0;                                                      \
    }                                                                                      \
    ROWP(BUF##0, _jb2, 0); ROWP(BUF##1, _jb2, 1); ROWP(BUF##2, _jb2, 2); ROWP(BUF##3, _jb2, 3); \
    ROWP(BUF##4, _jb2, 4); ROWP(BUF##5, _jb2, 5); ROWP(BUF##6, _jb2, 6); ROWP(BUF##7, _jb2, 7); \
} while (0)

__global__ __launch_bounds__(64) void k_walk(const float4* __restrict__ boxes,
                                             const float* __restrict__ scores,
                                             const uint64_t* __restrict__ supp,
                                             uint32_t* __restrict__ flags,
                                             uint32_t* __restrict__ tsave,
                                             uint64_t* __restrict__ aliveSv,
                                             float* __restrict__ out) {
    int b = blockIdx.x;
    int lane = threadIdx.x;
    const float4* bb = boxes + b * PRE;
    const float* sb = scores + b * PRE;
    const uint64_t* sbase = supp + (size_t)b * RROWS * NWSTRIDE;
    uint64_t v0, v1;
    if (lane < 46)       { v0 = ~0ull; v1 = ~0ull; }
    else if (lane == 46) { v0 = ~0ull; v1 = (1ull << 48) - 1ull; }  // words 92, 93(48 bits)
    else                 { v0 = 0ull;  v1 = 0ull; }
    uint64_t curw = 0;
    int t = 0;
    int flag = 0;
    ulonglong2 A0,A1,A2,A3,A4,A5,A6,A7;
    ulonglong2 B0,B1,B2,B3,B4,B5,B6,B7;
    ulonglong2 C0,C1,C2,C3,C4,C5,C6,C7;
    ISSUE(A, 0); ISSUE(B, 1); ISSUE(C, 2);
    for (int g = 0; g < NGROUPS; g += 3) {
        PROC(A, g);     ISSUE(A, g + 3);
        PROC(B, g + 1); ISSUE(B, g + 4);
        PROC(C, g + 2); ISSUE(C, g + 5);
    }
    // t < POST here: either everything below RROWS is dead, or alive bits remain >= RROWS
    {
        unsigned long long anyAlive = __ballot((v0 | v1) != 0ull);
        if (anyAlive == 0ull) {
            // reference semantics: argmax over all-NEG_INF returns 0 -> emit box 0 forever
            if (lane == 0) {
                float4 bc = bb[0];
                float s0 = sb[0];
                for (int tt = t; tt < POST; ++tt) {
                    size_t ob = ((size_t)b * POST + tt) * 4;
                    out[ob + 0] = bc.x; out[ob + 1] = bc.y;
                    out[ob + 2] = bc.z; out[ob + 3] = bc.w;
                    out[(size_t)NBATCH * POST * 4 + (size_t)b * POST + tt] = s0;
                }
            }
        } else {
            // checkpoint for exact serial resume
            if (2 * lane < NWORDS)     aliveSv[b * NWORDS + 2 * lane] = v0;
            if (2 * lane + 1 < NWORDS) aliveSv[b * NWORDS + 2 * lane + 1] = v1;
            if (lane == 0) tsave[b] = (uint32_t)t;
            flag = 1;
        }
    }
walk_done:
    if (lane == 0) flags[b] = (uint32_t)flag;
}

// ---------------- K6c: rare exact fallback; early-exits when flag==0 ----------------
__global__ __launch_bounds__(512) void k_resume(const float4* __restrict__ boxes,
                                                const float* __restrict__ scores,
                                                const uint32_t* __restrict__ flags,
                                                const uint32_t* __restrict__ tsave,
                                                const uint64_t* __restrict__ aliveSv,
                                                float* __restrict__ out) {
    int b = blockIdx.x;
    if (flags[b] == 0) return;
    __shared__ uint64_t alive[NWORDS];
    __shared__ uint32_t sCur;
    int tid = threadIdx.x;
    const float4* bb = boxes + b * PRE;
    const float* sb = scores + b * PRE;
    if (tid < NWORDS) alive[tid] = aliveSv[b * NWORDS + tid];
    __syncthreads();
    int t0 = (int)tsave[b];
    for (int t = t0; t < POST; ++t) {
        if (tid == 0) sCur = 0xFFFFFFFFu;
        __syncthreads();
        if (tid < NWORDS) {
            uint64_t wd = alive[tid];
            if (wd) atomicMin(&sCur, (uint32_t)(tid * 64 + (__ffsll((unsigned long long)wd) - 1)));
        }
        __syncthreads();
        uint32_t cur = sCur;
        uint32_t e = (cur < (uint32_t)PRE) ? cur : 0u;
        float4 bc = bb[e];
        if (tid == 0) {
            size_t ob = ((size_t)b * POST + t) * 4;
            out[ob + 0] = bc.x; out[ob + 1] = bc.y;
            out[ob + 2] = bc.z; out[ob + 3] = bc.w;
            out[(size_t)NBATCH * POST * 4 + (size_t)b * POST + t] = sb[e];
            if (cur < (uint32_t)PRE)
                atomicAnd(&alive[cur >> 6], ~(1ull << (cur & 63)));
        }
        if (cur < (uint32_t)PRE) {
            float areaC = __fmul_rn(__fadd_rn(__fsub_rn(bc.z, bc.x), 1.f),
                                    __fadd_rn(__fsub_rn(bc.w, bc.y), 1.f));
            for (uint32_t j = cur + 1 + tid; j < (uint32_t)PRE; j += 512) {
                uint64_t wd = alive[j >> 6];
                if ((wd >> (j & 63)) & 1ull) {
                    float4 bj = bb[j];
                    float xx1 = fmaxf(bc.x, bj.x);
                    float yy1 = fmaxf(bc.y, bj.y);
                    float xx2 = fminf(bc.z, bj.z);
                    float yy2 = fminf(bc.w, bj.w);
                    float iw = fmaxf(__fadd_rn(__fsub_rn(xx2, xx1), 1.f), 0.f);
                    float ih = fmaxf(__fadd_rn(__fsub_rn(yy2, yy1), 1.f), 0.f);
                    float inter = __fmul_rn(iw, ih);
                    float areaJ = __fmul_rn(__fadd_rn(__fsub_rn(bj.z, bj.x), 1.f),
                                            __fadd_rn(__fsub_rn(bj.w, bj.y), 1.f));
                    float uni = __fsub_rn(__fadd_rn(areaC, areaJ), inter);
                    if ((double)inter >= (double)uni * MIDP)
                        atomicAnd(&alive[j >> 6], ~(1ull << (j & 63)));
                }
            }
        }
        __syncthreads();
    }
}

extern "C" void kernel_launch(void* const* d_in, const int* in_sizes, int n_in,
                              void* d_out, int out_size, void* d_ws, size_t ws_size,
                              hipStream_t stream) {
    (void)in_sizes; (void)n_in; (void)out_size; (void)ws_size;
    const float* lab = (const float*)d_in[0];
    const float* reg = (const float*)d_in[1];
    float* out = (float*)d_out;
    char* ws = (char*)d_ws;

    // workspace layout (bytes)
    uint32_t* ghist  = (uint32_t*)(ws + 0);          // 524288
    uint32_t* cnt    = (uint32_t*)(ws + 524288);     // 64
    uint32_t* thr    = (uint32_t*)(ws + 524352);     // 64
    uint64_t* cand   = (uint64_t*)(ws + 524416);     // -> 1572992
    float4*   boxes  = (float4*)  (ws + 1572992);    // -> 3108992
    float*    scores = (float*)   (ws + 3108992);    // -> 3492992
    uint64_t* supp   = (uint64_t*)(ws + 3492992);    // 16*768*96*8 = 9437184 -> 12930176
    uint32_t* flags  = (uint32_t*)(ws + 12930176);   // 64
    uint32_t* tsave  = (uint32_t*)(ws + 12930240);   // 64
    uint64_t* aliveS = (uint64_t*)(ws + 12930304);   // -> 12942336
    uint32_t* keys   = (uint32_t*)(ws + 12942336);   // -> 31816704

    hipMemsetAsync(ws, 0, 524416, stream);           // zero ghist + cnt + thr

    k_hist   <<<256, 256, 0, stream>>>(lab, reg, ghist, keys);
    k_thresh <<<NBATCH, 256, 0, stream>>>(ghist, thr);
    k_compact<<<2048, 256, 0, stream>>>(keys, thr, cnt, cand);
    k_sort1  <<<NBATCH * 8, 256, 0, stream>>>(cnt, cand);
    k_sort2  <<<NBATCH, 1024, 0, stream>>>(cand, lab, reg, boxes, scores);
    k_iou    <<<256, 512, 0, stream>>>(boxes, supp);
    k_walk   <<<NBATCH, 64, 0, stream>>>(boxes, scores, supp, flags, tsave, aliveS, out);
    k_resume <<<NBATCH, 512, 0, stream>>>(boxes, scores, flags, tsave, aliveS, out);
}

// Round 9
// 354.322 us; speedup vs baseline: 6.6567x; 1.1173x over previous
//
#include <hip/hip_runtime.h>
#include <stdint.h>

#define NBATCH 16
#define NANCH  9
#define NHGT   128
#define NWID   256
#define NHW    (NHGT * NWID)       // 32768
#define NTOT   (NHW * NANCH)       // 294912
#define PRE    6000
#define POST   300
#define CAPN   8192
#define BINS   8192
#define BIN_SHIFT 19
#define NWORDS 94                  // ceil(6000/64)
#define NWSTRIDE 96                // padded row stride (words) -> 768 B, 16B-aligned
#define RROWS  768                 // suppression-matrix rows (exact fallback beyond)
#define NGROUPS (RROWS / 8)        // 96 groups of 8 rows
#define JHALF  3072                // j-split point for k_iou (words 0..47 | 48..93)
#define JREM   (PRE - JHALF)       // 2928

// exact replacement for (div_rn(inter,uni) > 0.7f):  (double)inter >= (double)uni * M
// M = midpoint(0.7f, nextafterf(0.7f)); tie rounds to even mantissa (0x3F333334) > 0.7f.
#define MIDP 0x1.6666668p-1

__device__ __constant__ float c_AW[NANCH] = {184.f,368.f,736.f,128.f,256.f,512.f,88.f,176.f,352.f};
__device__ __constant__ float c_AH[NANCH] = {96.f,192.f,384.f,128.f,256.f,512.f,176.f,352.f,704.f};

__device__ __forceinline__ uint32_t f2key(float f) {
    uint32_t u = __float_as_uint(f);
    return (u & 0x80000000u) ? ~u : (u | 0x80000000u);
}

__device__ __forceinline__ bool decode_clip(float dx, float dy, float dw, float dh,
                                            float aw, float ah, float acx, float acy,
                                            float& x1, float& y1, float& x2, float& y2) {
    float pcx = __fadd_rn(__fmul_rn(dx, aw), acx);
    float pcy = __fadd_rn(__fmul_rn(dy, ah), acy);
    float pw  = __fmul_rn(expf(dw), aw);
    float ph  = __fmul_rn(expf(dh), ah);
    float hx  = __fmul_rn(0.5f, pw);
    float hy  = __fmul_rn(0.5f, ph);
    x1 = __fsub_rn(pcx, hx);
    y1 = __fsub_rn(pcy, hy);
    x2 = __fadd_rn(pcx, hx);
    y2 = __fadd_rn(pcy, hy);
    x1 = fminf(fmaxf(x1, 0.f), 4095.f);
    x2 = fminf(fmaxf(x2, 0.f), 4095.f);
    y1 = fminf(fmaxf(y1, 0.f), 2047.f);
    y2 = fminf(fmaxf(y2, 0.f), 2047.f);
    float wpl = __fadd_rn(__fsub_rn(x2, x1), 1.f);
    float hpl = __fadd_rn(__fsub_rn(y2, y1), 1.f);
    return (wpl >= 16.f) && (hpl >= 16.f);
}

// ---------------- K1: LDS histogram + emit per-anchor key array ----------------
__global__ __launch_bounds__(256) void k_hist(const float* __restrict__ lab,
                                              const float* __restrict__ reg,
                                              uint32_t* __restrict__ ghist,
                                              uint32_t* __restrict__ keys) {
    __shared__ uint32_t hist[BINS];
    for (int i = threadIdx.x; i < BINS; i += 256) hist[i] = 0;
    __syncthreads();
    int b = blockIdx.x >> 4, sub = blockIdx.x & 15;
    const float* lb0 = lab + (size_t)b * 18 * NHW;
    const float* rb0 = reg + (size_t)b * 36 * NHW;
    uint32_t* kb = keys + (size_t)b * NANCH * NHW;
    for (int k = 0; k < 8; ++k) {
        int hw = ((sub * 8 + k) << 8) | threadIdx.x;
        int h = hw >> 8, w = hw & 255;
        const float* lb = lb0 + hw;
        const float* rb = rb0 + hw;
        float acx = (float)(w * 16) + 7.5f;
        float acy = (float)(h * 16) + 7.5f;
#pragma unroll
        for (int a = 0; a < NANCH; ++a) {
            float s  = lb[(2 * a + 1) * NHW];
            float dx = rb[(4 * a + 0) * NHW];
            float dy = rb[(4 * a + 1) * NHW];
            float dwv = rb[(4 * a + 2) * NHW];
            float dhv = rb[(4 * a + 3) * NHW];
            float x1, y1, x2, y2;
            bool keep = decode_clip(dx, dy, dwv, dhv, c_AW[a], c_AH[a], acx, acy, x1, y1, x2, y2);
            float ms = keep ? s : -1e30f;
            uint32_t key = f2key(ms);
            kb[a * NHW + hw] = key;
            atomicAdd(&hist[key >> BIN_SHIFT], 1u);
        }
    }
    __syncthreads();
    uint32_t* gh = ghist + ((size_t)b << 13);
    for (int i = threadIdx.x; i < BINS; i += 256) {
        uint32_t c = hist[i];
        if (c) atomicAdd(&gh[i], c);
    }
}

// ---------------- K2: find threshold bin (cumulative from top >= PRE) ----------------
__global__ __launch_bounds__(256) void k_thresh(const uint32_t* __restrict__ ghist,
                                                uint32_t* __restrict__ thresh) {
    __shared__ uint32_t part[256];
    int b = blockIdx.x;
    const uint32_t* gh = ghist + ((size_t)b << 13);
    uint32_t p = 0;
    int base = threadIdx.x * 32;
    for (int k = 0; k < 32; ++k) p += gh[base + k];
    part[threadIdx.x] = p;
    __syncthreads();
    if (threadIdx.x == 0) {
        uint32_t cum = 0;
        int tb = 0;
        for (int c = 255; c >= 0; --c) {
            if (cum + part[c] >= (uint32_t)PRE) {
                for (int i = 31; i >= 0; --i) {
                    cum += gh[c * 32 + i];
                    if (cum >= (uint32_t)PRE) { tb = c * 32 + i; break; }
                }
                break;
            }
            cum += part[c];
        }
        thresh[b] = (uint32_t)tb << BIN_SHIFT;
    }
}

// ---------------- K3: compact from key array; LDS staging, 1 atomic/block ----------------
__global__ __launch_bounds__(256) void k_compact(const uint32_t* __restrict__ keys,
                                                 const uint32_t* __restrict__ thresh,
                                                 uint32_t* __restrict__ cnt,
                                                 uint64_t* __restrict__ cand) {
    __shared__ uint64_t stage[2304];
    __shared__ uint32_t sCount;
    __shared__ uint32_t sBase;
    if (threadIdx.x == 0) sCount = 0;
    __syncthreads();
    int bid = blockIdx.x;
    int b = bid >> 7;
    int hw = ((bid & 127) << 8) | threadIdx.x;
    int lane = threadIdx.x & 63;
    const uint32_t* kb = keys + (size_t)b * NANCH * NHW + hw;
    uint32_t th = thresh[b];
#pragma unroll
    for (int a = 0; a < NANCH; ++a) {
        uint32_t key = kb[a * NHW];
        bool valid = (key >= th);
        uint64_t mask = __ballot(valid);
        if (mask) {
            int leader = __ffsll((unsigned long long)mask) - 1;
            uint32_t wb = 0;
            if (lane == leader) wb = atomicAdd(&sCount, (uint32_t)__popcll(mask));
            wb = (uint32_t)__shfl((int)wb, leader);
            if (valid) {
                int rank = __popcll(mask & ((1ull << lane) - 1ull));
                uint32_t n = (uint32_t)(hw * NANCH + a);
                stage[wb + rank] = ((uint64_t)key << 32) | (uint32_t)(~n);
            }
        }
    }
    __syncthreads();
    if (threadIdx.x == 0) sBase = atomicAdd(&cnt[b], sCount);
    __syncthreads();
    uint32_t total = sCount, base = sBase;
    for (uint32_t i = threadIdx.x; i < total; i += 256) {
        uint32_t pos = base + i;
        if (pos < (uint32_t)CAPN) cand[(size_t)b * CAPN + pos] = stage[i];
    }
}

// ---------------- K4a: bitonic phases k=2..2048 within each 2048-chunk ----------------
// grid = 16 batches x 4 chunks = 64 blocks, 512 threads; canonical network preserved
__global__ __launch_bounds__(512) void k_sort1(const uint32_t* __restrict__ cnt,
                                               uint64_t* __restrict__ cand) {
    __shared__ uint64_t sm[2048];            // 16 KiB
    int b = blockIdx.x >> 2, c = blockIdx.x & 3;
    uint32_t C = cnt[b];
    if (C > (uint32_t)CAPN) C = CAPN;
    uint64_t* cb = cand + (size_t)b * CAPN;
    int base = c << 11;
    for (int li = threadIdx.x; li < 2048; li += 512) {
        int gi = base + li;
        sm[li] = (gi < (int)C) ? cb[gi] : 0ull;
    }
    __syncthreads();
    for (int k = 2; k <= 2048; k <<= 1) {
        for (int j = k >> 1; j > 0; j >>= 1) {
            for (int li = threadIdx.x; li < 2048; li += 512) {
                int lxj = li ^ j;
                if (lxj > li) {
                    int gi = base + li;                       // global index for direction
                    uint64_t va = sm[li], vb = sm[lxj];
                    bool up = ((gi & k) == 0);
                    bool sw = up ? (va < vb) : (va > vb);
                    if (sw) { sm[li] = vb; sm[lxj] = va; }
                }
            }
            __syncthreads();
        }
    }
    for (int li = threadIdx.x; li < 2048; li += 512) cb[base + li] = sm[li];
}

// ---------------- K4b: merge phases k=4096..8192 + fused gather/decode ----------------
__global__ __launch_bounds__(1024) void k_sort2(const uint64_t* __restrict__ cand,
                                                const float* __restrict__ lab,
                                                const float* __restrict__ reg,
                                                float4* __restrict__ boxes,
                                                float* __restrict__ scores) {
    __shared__ uint64_t sm[CAPN];
    int b = blockIdx.x;
    const uint64_t* cb = cand + (size_t)b * CAPN;
    for (int i = threadIdx.x; i < CAPN; i += 1024) sm[i] = cb[i];
    __syncthreads();
    for (int k = 4096; k <= CAPN; k <<= 1) {
        for (int j = k >> 1; j > 0; j >>= 1) {
            for (int i = threadIdx.x; i < CAPN; i += 1024) {
                int ixj = i ^ j;
                if (ixj > i) {
                    uint64_t va = sm[i], vb = sm[ixj];
                    bool up = ((i & k) == 0);
                    bool sw = up ? (va < vb) : (va > vb);
                    if (sw) { sm[i] = vb; sm[ixj] = va; }
                }
            }
            __syncthreads();
        }
    }
    const float* lb0 = lab + (size_t)b * 18 * NHW;
    const float* rb0 = reg + (size_t)b * 36 * NHW;
    for (int p = threadIdx.x; p < PRE; p += 1024) {
        uint32_t n = ~(uint32_t)(sm[p] & 0xFFFFFFFFull);
        if (n >= (uint32_t)NTOT) n = 0;
        int a = (int)(n % NANCH);
        int hw = (int)(n / NANCH);
        int w = hw & 255, h = hw >> 8;
        float s  = lb0[(2 * a + 1) * NHW + hw];
        float dx = rb0[(4 * a + 0) * NHW + hw];
        float dy = rb0[(4 * a + 1) * NHW + hw];
        float dwv = rb0[(4 * a + 2) * NHW + hw];
        float dhv = rb0[(4 * a + 3) * NHW + hw];
        float acx = (float)(w * 16) + 7.5f;
        float acy = (float)(h * 16) + 7.5f;
        float x1, y1, x2, y2;
        decode_clip(dx, dy, dwv, dhv, c_AW[a], c_AH[a], acx, acy, x1, y1, x2, y2);
        boxes[b * PRE + p] = make_float4(x1, y1, x2, y2);
        scores[b * PRE + p] = s;
    }
}

// ---------------- K6a: suppression bit-matrix, j-split halves for 2 blocks/CU ----------------
// grid = b(4b) | rblk(4b) | half(1b) = 512 blocks, 512 thr, ~61KB LDS each.
// half 0: words 0..47 (j<3072); half 1: words 48..93 (j>=3072) + pad 94,95.
__global__ __launch_bounds__(512) void k_iou(const float4* __restrict__ boxes,
                                             uint64_t* __restrict__ supp) {
    __shared__ float4 lb[JHALF];             // 49152 B
    __shared__ float  la[JHALF];             // 12288 B
    int half = blockIdx.x & 1;
    int rblk = (blockIdx.x >> 1) & 15;
    int b    = blockIdx.x >> 5;
    const float4* bb = boxes + b * PRE;
    int jbase  = half ? JHALF : 0;
    int jcount = half ? JREM : JHALF;
    for (int i = threadIdx.x; i < jcount; i += 512) {
        float4 v = bb[jbase + i];
        lb[i] = v;
        la[i] = __fmul_rn(__fadd_rn(__fsub_rn(v.z, v.x), 1.f),
                          __fadd_rn(__fsub_rn(v.w, v.y), 1.f));
    }
    __syncthreads();
    int wave = threadIdx.x >> 6, lane = threadIdx.x & 63;
    int wlo = half ? 48 : 0;
    int whi = half ? NWORDS : 48;
#pragma unroll 1
    for (int m = 0; m < 6; ++m) {
        int r = rblk + 16 * wave + 128 * m;   // < RROWS, bijective
        float4 bi = bb[r];                    // row box may live in the other half
        float areaI = __fmul_rn(__fadd_rn(__fsub_rn(bi.z, bi.x), 1.f),
                                __fadd_rn(__fsub_rn(bi.w, bi.y), 1.f));
        uint64_t keep = 0ull;
        int w0 = r >> 6;                      // <= 11
        int wstart = (wlo > w0) ? wlo : w0;
        for (int w = wstart; w < whi; ++w) {
            int j = (w << 6) | lane;
            bool sup = false;
            if (j < PRE) {
                int idx = j - jbase;
                float4 bj = lb[idx];
                float xx1 = fmaxf(bi.x, bj.x);
                float yy1 = fmaxf(bi.y, bj.y);
                float xx2 = fminf(bi.z, bj.z);
                float yy2 = fminf(bi.w, bj.w);
                float iw = fmaxf(__fadd_rn(__fsub_rn(xx2, xx1), 1.f), 0.f);
                float ih = fmaxf(__fadd_rn(__fsub_rn(yy2, yy1), 1.f), 0.f);
                float inter = __fmul_rn(iw, ih);
                float uni = __fsub_rn(__fadd_rn(areaI, la[idx]), inter);
                sup = ((double)inter >= (double)uni * MIDP);
            }
            uint64_t mball = __ballot(sup);
            if (lane == w - wlo) keep = mball;
        }
        uint64_t* srow = supp + ((size_t)b * RROWS + r) * NWSTRIDE;
        if (half == 0) {
            if (lane < 48) srow[lane] = keep;           // words 0..47 (0 below w0)
        } else {
            if (lane < 48) srow[48 + lane] = (lane < 46) ? keep : 0ull;  // 48..93 + pad
        }
    }
}

// ---------------- K6b: sequential-row walk, triple-buffered static prefetch ----------------
// lane l<48 owns words 2l,2l+1 (bits 128l..128l+127); lane 48 carries box, lane 49 score.
#define SETLOX(V, F) V.x = (uint64_t)__float_as_uint(F)

#define ISSUE(BUF, GRP) do {                                                               \
    int _g = (GRP); if (_g > NGROUPS - 1) _g = NGROUPS - 1;                                \
    int _jb = _g << 3;                                                                     \
    if (lane < 48) {                                                                       \
        const ulonglong2* _p = (const ulonglong2*)(sbase + (size_t)_jb * NWSTRIDE) + lane; \
        BUF##0 = _p[0];   BUF##1 = _p[48];  BUF##2 = _p[96];  BUF##3 = _p[144];            \
        BUF##4 = _p[192]; BUF##5 = _p[240]; BUF##6 = _p[288]; BUF##7 = _p[336];            \
    } else if (lane == 48) {                                                               \
        const ulonglong2* _q = (const ulonglong2*)(bb + _jb);                              \
        BUF##0 = _q[0]; BUF##1 = _q[1]; BUF##2 = _q[2]; BUF##3 = _q[3];                    \
        BUF##4 = _q[4]; BUF##5 = _q[5]; BUF##6 = _q[6]; BUF##7 = _q[7];                    \
    } else if (lane == 49) {                                                               \
        const float* _s = sb + _jb;                                                        \
        SETLOX(BUF##0, _s[0]); SETLOX(BUF##1, _s[1]);                                      \
        SETLOX(BUF##2, _s[2]); SETLOX(BUF##3, _s[3]);                                      \
        SETLOX(BUF##4, _s[4]); SETLOX(BUF##5, _s[5]);                                      \
        SETLOX(BUF##6, _s[6]); SETLOX(BUF##7, _s[7]);                                      \
    }                                                                                      \
} while (0)

#define ROWP(RD, JB, R) {                                                                  \
    if (((curw >> (((JB) & 63) + (R))) & 1ull) != 0ull) {                                  \
        uint64_t _b0 = (uint64_t)__shfl((long long)RD.x, 48);                              \
        uint64_t _b1 = (uint64_t)__shfl((long long)RD.y, 48);                              \
        uint32_t _sc = (uint32_t)(uint64_t)__shfl((long long)RD.x, 49);                    \
        if (lane == 0) {                                                                   \
            size_t _ob = ((size_t)b * POST + t) * 4;                                       \
            out[_ob + 0] = __uint_as_float((uint32_t)_b0);                                 \
            out[_ob + 1] = __uint_as_float((uint32_t)(_b0 >> 32));                         \
            out[_ob + 2] = __uint_as_float((uint32_t)_b1);                                 \
            out[_ob + 3] = __uint_as_float((uint32_t)(_b1 >> 32));                         \
            out[(size_t)NBATCH * POST * 4 + (size_t)b * POST + t] = __uint_as_float(_sc);  \
        }                                                                                  \
        v0 &= ~RD.x; v1 &= ~RD.y;                                                          \
        int _w = ((JB) + (R)) >> 6;                                                        \
        uint64_t _sw = (uint64_t)__shfl((long long)((_w & 1) ? RD.y : RD.x), _w >> 1);     \
        curw &= ~_sw;                                                                      \
        ++t;                                                                               \
        if (t >= POST) goto walk_done;                                                     \
    }                                                                                      \
}

#define PROC(BUF, GRP) do {                                                                \
    int _jb2 = (GRP) << 3;                                                                 \
    if ((_jb2 & 63) == 0) {                                                                \
        int _wi = _jb2 >> 6;                                                               \
        uint64_t _c0 = (uint64_t)__shfl((long long)v0, _wi >> 1);                          \
        uint64_t _c1 = (uint64_t)__shfl((long long)v1, _wi >> 1);                          \
        curw = (_wi & 1) ? _c1 : _c0;                                                      \
    }                                                                                      \
    ROWP(BUF##0, _jb2, 0); ROWP(BUF##1, _jb2, 1); ROWP(BUF##2, _jb2, 2); ROWP(BUF##3, _jb2, 3); \
    ROWP(BUF##4, _jb2, 4); ROWP(BUF##5, _jb2, 5); ROWP(BUF##6, _jb2, 6); ROWP(BUF##7, _jb2, 7); \
} while (0)

__global__ __launch_bounds__(64) void k_walk(const float4* __restrict__ boxes,
                                             const float* __restrict__ scores,
                                             const uint64_t* __restrict__ supp,
                                             uint32_t* __restrict__ flags,
                                             uint32_t* __restrict__ tsave,
                                             uint64_t* __restrict__ aliveSv,
                                             float* __restrict__ out) {
    int b = blockIdx.x;
    int lane = threadIdx.x;
    const float4* bb = boxes + b * PRE;
    const float* sb = scores + b * PRE;
    const uint64_t* sbase = supp + (size_t)b * RROWS * NWSTRIDE;
    uint64_t v0, v1;
    if (lane < 46)       { v0 = ~0ull; v1 = ~0ull; }
    else if (lane == 46) { v0 = ~0ull; v1 = (1ull << 48) - 1ull; }  // words 92, 93(48 bits)
    else                 { v0 = 0ull;  v1 = 0ull; }
    uint64_t curw = 0;
    int t = 0;
    int flag = 0;
    ulonglong2 A0,A1,A2,A3,A4,A5,A6,A7;
    ulonglong2 B0,B1,B2,B3,B4,B5,B6,B7;
    ulonglong2 C0,C1,C2,C3,C4,C5,C6,C7;
    ISSUE(A, 0); ISSUE(B, 1); ISSUE(C, 2);
    for (int g = 0; g < NGROUPS; g += 3) {
        PROC(A, g);     ISSUE(A, g + 3);
        PROC(B, g + 1); ISSUE(B, g + 4);
        PROC(C, g + 2); ISSUE(C, g + 5);
    }
    // t < POST here: either everything below RROWS is dead, or alive bits remain >= RROWS
    {
        unsigned long long anyAlive = __ballot((v0 | v1) != 0ull);
        if (anyAlive == 0ull) {
            // reference semantics: argmax over all-NEG_INF returns 0 -> emit box 0 forever
            if (lane == 0) {
                float4 bc = bb[0];
                float s0 = sb[0];
                for (int tt = t; tt < POST; ++tt) {
                    size_t ob = ((size_t)b * POST + tt) * 4;
                    out[ob + 0] = bc.x; out[ob + 1] = bc.y;
                    out[ob + 2] = bc.z; out[ob + 3] = bc.w;
                    out[(size_t)NBATCH * POST * 4 + (size_t)b * POST + tt] = s0;
                }
            }
        } else {
            // checkpoint for exact serial resume
            if (2 * lane < NWORDS)     aliveSv[b * NWORDS + 2 * lane] = v0;
            if (2 * lane + 1 < NWORDS) aliveSv[b * NWORDS + 2 * lane + 1] = v1;
            if (lane == 0) tsave[b] = (uint32_t)t;
            flag = 1;
        }
    }
walk_done:
    if (lane == 0) flags[b] = (uint32_t)flag;
}

// ---------------- K6c: rare exact fallback; early-exits when flag==0 ----------------
__global__ __launch_bounds__(512) void k_resume(const float4* __restrict__ boxes,
                                                const float* __restrict__ scores,
                                                const uint32_t* __restrict__ flags,
                                                const uint32_t* __restrict__ tsave,
                                                const uint64_t* __restrict__ aliveSv,
                                                float* __restrict__ out) {
    int b = blockIdx.x;
    if (flags[b] == 0) return;
    __shared__ uint64_t alive[NWORDS];
    __shared__ uint32_t sCur;
    int tid = threadIdx.x;
    const float4* bb = boxes + b * PRE;
    const float* sb = scores + b * PRE;
    if (tid < NWORDS) alive[tid] = aliveSv[b * NWORDS + tid];
    __syncthreads();
    int t0 = (int)tsave[b];
    for (int t = t0; t < POST; ++t) {
        if (tid == 0) sCur = 0xFFFFFFFFu;
        __syncthreads();
        if (tid < NWORDS) {
            uint64_t wd = alive[tid];
            if (wd) atomicMin(&sCur, (uint32_t)(tid * 64 + (__ffsll((unsigned long long)wd) - 1)));
        }
        __syncthreads();
        uint32_t cur = sCur;
        uint32_t e = (cur < (uint32_t)PRE) ? cur : 0u;
        float4 bc = bb[e];
        if (tid == 0) {
            size_t ob = ((size_t)b * POST + t) * 4;
            out[ob + 0] = bc.x; out[ob + 1] = bc.y;
            out[ob + 2] = bc.z; out[ob + 3] = bc.w;
            out[(size_t)NBATCH * POST * 4 + (size_t)b * POST + t] = sb[e];
            if (cur < (uint32_t)PRE)
                atomicAnd(&alive[cur >> 6], ~(1ull << (cur & 63)));
        }
        if (cur < (uint32_t)PRE) {
            float areaC = __fmul_rn(__fadd_rn(__fsub_rn(bc.z, bc.x), 1.f),
                                    __fadd_rn(__fsub_rn(bc.w, bc.y), 1.f));
            for (uint32_t j = cur + 1 + tid; j < (uint32_t)PRE; j += 512) {
                uint64_t wd = alive[j >> 6];
                if ((wd >> (j & 63)) & 1ull) {
                    float4 bj = bb[j];
                    float xx1 = fmaxf(bc.x, bj.x);
                    float yy1 = fmaxf(bc.y, bj.y);
                    float xx2 = fminf(bc.z, bj.z);
                    float yy2 = fminf(bc.w, bj.w);
                    float iw = fmaxf(__fadd_rn(__fsub_rn(xx2, xx1), 1.f), 0.f);
                    float ih = fmaxf(__fadd_rn(__fsub_rn(yy2, yy1), 1.f), 0.f);
                    float inter = __fmul_rn(iw, ih);
                    float areaJ = __fmul_rn(__fadd_rn(__fsub_rn(bj.z, bj.x), 1.f),
                                            __fadd_rn(__fsub_rn(bj.w, bj.y), 1.f));
                    float uni = __fsub_rn(__fadd_rn(areaC, areaJ), inter);
                    if ((double)inter >= (double)uni * MIDP)
                        atomicAnd(&alive[j >> 6], ~(1ull << (j & 63)));
                }
            }
        }
        __syncthreads();
    }
}

extern "C" void kernel_launch(void* const* d_in, const int* in_sizes, int n_in,
                              void* d_out, int out_size, void* d_ws, size_t ws_size,
                              hipStream_t stream) {
    (void)in_sizes; (void)n_in; (void)out_size; (void)ws_size;
    const float* lab = (const float*)d_in[0];
    const float* reg = (const float*)d_in[1];
    float* out = (float*)d_out;
    char* ws = (char*)d_ws;

    // workspace layout (bytes)
    uint32_t* ghist  = (uint32_t*)(ws + 0);          // 524288
    uint32_t* cnt    = (uint32_t*)(ws + 524288);     // 64
    uint32_t* thr    = (uint32_t*)(ws + 524352);     // 64
    uint64_t* cand   = (uint64_t*)(ws + 524416);     // -> 1572992
    float4*   boxes  = (float4*)  (ws + 1572992);    // -> 3108992
    float*    scores = (float*)   (ws + 3108992);    // -> 3492992
    uint64_t* supp   = (uint64_t*)(ws + 3492992);    // 16*768*96*8 = 9437184 -> 12930176
    uint32_t* flags  = (uint32_t*)(ws + 12930176);   // 64
    uint32_t* tsave  = (uint32_t*)(ws + 12930240);   // 64
    uint64_t* aliveS = (uint64_t*)(ws + 12930304);   // -> 12942336
    uint32_t* keys   = (uint32_t*)(ws + 12942336);   // -> 31816704

    hipMemsetAsync(ws, 0, 524416, stream);           // zero ghist + cnt + thr

    k_hist   <<<256, 256, 0, stream>>>(lab, reg, ghist, keys);
    k_thresh <<<NBATCH, 256, 0, stream>>>(ghist, thr);
    k_compact<<<2048, 256, 0, stream>>>(keys, thr, cnt, cand);
    k_sort1  <<<NBATCH * 4, 512, 0, stream>>>(cnt, cand);
    k_sort2  <<<NBATCH, 1024, 0, stream>>>(cand, lab, reg, boxes, scores);
    k_iou    <<<NBATCH * 32, 512, 0, stream>>>(boxes, supp);
    k_walk   <<<NBATCH, 64, 0, stream>>>(boxes, scores, supp, flags, tsave, aliveS, out);
    k_resume <<<NBATCH, 512, 0, stream>>>(boxes, scores, flags, tsave, aliveS, out);
}